// Round 10
// baseline (1006.661 us; speedup 1.0000x reference)
//
#include <hip/hip_runtime.h>
#include <hip/hip_bf16.h>

#define N_NODES 100000
#define N_PAD   100032          // 1563 * 64
#define N_EDGES 1600000
#define DIM 128
#define N_GRAPHS 128
#define NBKT 98                 // ceil(100000/1024)
#define BSTRIDE 18432           // bucket capacity (mean 16384, +16 sigma)
#define TILES (N_PAD / 16)      // 6252 row-tiles of 16 (even)
#define GRID_MLP 1024
#define POOL_BLKS ((N_NODES + 127) / 128)   // 782
#define SSTRIDE ((size_t)N_PAD * 16)        // u16 elems per 16-col slice plane
#define AGG_BPS 391                          // agg blocks per slice

typedef unsigned short u16;
typedef unsigned int u32;
typedef __attribute__((ext_vector_type(8))) short bf16x8;
typedef __attribute__((ext_vector_type(4))) float f32x4;

#define MFMA(A, B, C) __builtin_amdgcn_mfma_f32_16x16x32_bf16(A, B, C, 0, 0, 0)

__device__ __forceinline__ u16 f2bf(float x) {
    u32 u = __float_as_uint(x);
    u = (u + 0x7FFFu + ((u >> 16) & 1u)) >> 16;
    return (u16)u;
}
__device__ __forceinline__ float bf2f(u16 u) {
    return __uint_as_float(((u32)u) << 16);
}
// unpack packed 2xbf16 word
__device__ __forceinline__ float bfLo(u32 v) { return __uint_as_float(v << 16); }
__device__ __forceinline__ float bfHi(u32 v) { return __uint_as_float(v & 0xFFFF0000u); }

// ===========================================================================
// bucket phase 1: append packed (dstLocal<<22 | src) to coarse buckets.
// ===========================================================================
__global__ __launch_bounds__(256) void bucket1_kernel(const int* __restrict__ src,
                                                      const int* __restrict__ dst,
                                                      u32* __restrict__ cursorB,
                                                      u32* __restrict__ pairs) {
    __shared__ int lh[NBKT];
    __shared__ u32 lbase[NBKT];
    int t = threadIdx.x;
    if (t < NBKT) lh[t] = 0;
    __syncthreads();
    int e0 = blockIdx.x * 1024;
    int d[4], s[4], rk[4], bk[4];
#pragma unroll
    for (int k = 0; k < 4; ++k) {
        int e = e0 + t + k * 256;
        if (e < N_EDGES) {
            d[k] = dst[e];
            s[k] = src[e];
            bk[k] = d[k] >> 10;
            rk[k] = atomicAdd(&lh[bk[k]], 1);
        }
    }
    __syncthreads();
    if (t < NBKT) lbase[t] = atomicAdd(&cursorB[t], (u32)lh[t]) + (u32)(t * BSTRIDE);
    __syncthreads();
#pragma unroll
    for (int k = 0; k < 4; ++k) {
        int e = e0 + t + k * 256;
        if (e < N_EDGES) {
            u32 pos = lbase[bk[k]] + (u32)rk[k];
            pairs[pos] = ((u32)(d[k] & 1023) << 22) | (u32)s[k];
        }
    }
}

// ===========================================================================
// bucket phase 2: per-bucket hist + scan -> row_ptr, then scatter into csr.
// ===========================================================================
__global__ __launch_bounds__(1024) void bucket2_kernel(const u32* __restrict__ cursorB,
                                                       const u32* __restrict__ pairs,
                                                       int* __restrict__ row_ptr,
                                                       int* __restrict__ csr) {
    __shared__ int lh[1024];
    __shared__ int rc[1024];
    __shared__ int bs[128];
    int b = blockIdx.x, t = threadIdx.x;

    if (t < 128) bs[t] = (t < NBKT) ? (int)cursorB[t] : 0;
    __syncthreads();
    for (int off = 1; off < 128; off <<= 1) {
        int v = (t < 128 && t >= off) ? bs[t - off] : 0;
        __syncthreads();
        if (t < 128) bs[t] += v;
        __syncthreads();
    }
    int cnt = (int)cursorB[b];
    int bbase = (b == 0) ? 0 : bs[b - 1];

    lh[t] = 0;
    __syncthreads();
    const u32* pb = pairs + (size_t)b * BSTRIDE;
    for (int i = t; i < cnt; i += 1024) atomicAdd(&lh[pb[i] >> 22], 1);
    __syncthreads();

    int own = lh[t];
    for (int off = 1; off < 1024; off <<= 1) {
        int v = (t >= off) ? lh[t - off] : 0;
        __syncthreads();
        lh[t] += v;
        __syncthreads();
    }
    int excl = lh[t] - own;
    int node = b * 1024 + t;
    if (node < N_NODES) row_ptr[node] = bbase + excl;
    if (b == 0 && t == 0) row_ptr[N_NODES] = N_EDGES;
    rc[t] = bbase + excl;
    __syncthreads();

    for (int i = t; i < cnt; i += 1024) {
        u32 p = pb[i];
        int pos = atomicAdd(&rc[p >> 22], 1);
        csr[pos] = (int)(p & 0x3FFFFFu);
    }
}

// ===========================================================================
// x -> bf16 hi plane, column-sliced layout:
// elem(node,col) at hb[(col>>4)*SSTRIDE + node*16 + (col&15)]
// ===========================================================================
__global__ __launch_bounds__(256) void xprep_kernel(const float* __restrict__ x,
                                                    u16* __restrict__ hb) {
    int i = blockIdx.x * 256 + threadIdx.x;
    if (i < N_NODES * 32) {
        int node = i >> 5;
        int cg = i & 31;               // float4 group; col0 = cg*4
        float4 v = ((const float4*)x)[i];
        ushort4 o;
        o.x = f2bf(v.x); o.y = f2bf(v.y); o.z = f2bf(v.z); o.w = f2bf(v.w);
        int slice = cg >> 2;
        int within = (cg & 3) * 4;
        *(ushort4*)(hb + (size_t)slice * SSTRIDE + (size_t)node * 16 + within) = o;
    }
}

// ===========================================================================
// aggregation, XCD-sliced: block handles one 16-col slice (blockIdx%8 -> XCD
// heuristic). Half-wave (32 lanes) per node = 4 neighbors x 8 lanes (ushort2).
// csr via nontemporal loads; Ah/Al via nontemporal stores (keep h slice in L2).
// ===========================================================================
__global__ __launch_bounds__(256) void agg_kernel(const u16* __restrict__ hb,
                                                  const int* __restrict__ rp,
                                                  const int* __restrict__ csr,
                                                  u16* __restrict__ Ah,
                                                  u16* __restrict__ Al) {
    int slice = blockIdx.x & 7;
    int bchunk = blockIdx.x >> 3;
    int hw = threadIdx.x >> 5;          // half-wave 0..7 -> node within chunk
    int l = threadIdx.x & 31;
    int q = l >> 3;                     // neighbor sub-slot 0..3
    int c = l & 7;                      // column pair 0..7 (cols c*2, c*2+1)
    const u16* hs = hb + (size_t)slice * SSTRIDE;
    u16* AhS = Ah + (size_t)slice * SSTRIDE;
    u16* AlS = Al + (size_t)slice * SSTRIDE;
    const int strideN = AGG_BPS * 8;

    for (int node = bchunk * 8 + hw; node < N_NODES; node += strideN) {
        int s = rp[node], e = rp[node + 1];
        float a0 = 0.f, a1 = 0.f;
        if (q == 0) {
            u32 sv = *(const u32*)(hs + (size_t)node * 16 + c * 2);
            a0 = bfLo(sv); a1 = bfHi(sv);
        }
        int i = s;
        for (; i + 8 <= e; i += 8) {
            int iA = __builtin_nontemporal_load(csr + i + q);
            int iB = __builtin_nontemporal_load(csr + i + 4 + q);
            u32 vA = *(const u32*)(hs + (size_t)iA * 16 + c * 2);
            u32 vB = *(const u32*)(hs + (size_t)iB * 16 + c * 2);
            a0 += bfLo(vA) + bfLo(vB);
            a1 += bfHi(vA) + bfHi(vB);
        }
        for (; i < e; i += 4) {
            if (i + q < e) {
                int iA = __builtin_nontemporal_load(csr + i + q);
                u32 vA = *(const u32*)(hs + (size_t)iA * 16 + c * 2);
                a0 += bfLo(vA);
                a1 += bfHi(vA);
            }
        }
        // reduce across the 4 neighbor sub-slots (lanes l, l^8, l^16(^24))
        a0 += __shfl_xor(a0, 8);  a1 += __shfl_xor(a1, 8);
        a0 += __shfl_xor(a0, 16); a1 += __shfl_xor(a1, 16);
        if (q == 0) {
            u16 h0 = f2bf(a0), h1 = f2bf(a1);
            u16 l0 = f2bf(a0 - bf2f(h0)), l1 = f2bf(a1 - bf2f(h1));
            u32 hv = (u32)h0 | ((u32)h1 << 16);
            u32 lv = (u32)l0 | ((u32)l1 << 16);
            __builtin_nontemporal_store(hv, (u32*)(AhS + (size_t)node * 16 + c * 2));
            __builtin_nontemporal_store(lv, (u32*)(AlS + (size_t)node * 16 + c * 2));
        }
    }
}

// ===========================================================================
// W prep: fp32 W[k][n] -> WT planes: hi at [n*128+k], lo at [n*128+k + 16384]
// ===========================================================================
struct WPrepArgs {
    const float* w[6];
    u16* buf[6];
};
__global__ __launch_bounds__(256) void wprep_kernel(WPrepArgs p) {
    int m = blockIdx.y;
    int idx = blockIdx.x * 256 + threadIdx.x;   // n*128 + k
    int n = idx >> 7, k = idx & 127;
    float v = p.w[m][k * 128 + n];
    u16 hi = f2bf(v);
    p.buf[m][idx] = hi;
    p.buf[m][idx + 16384] = f2bf(v - bf2f(hi));
}

// ===========================================================================
// fused MLP, W-in-registers, 2 row-tiles/iter; act planes column-sliced.
// ===========================================================================
#define HS 136
__global__ __launch_bounds__(256, 2) void fused_mlp(const u16* __restrict__ Ah,
                                                    const u16* __restrict__ Al,
                                                    const u16* __restrict__ W1,
                                                    const float* __restrict__ b1,
                                                    const u16* __restrict__ W2,
                                                    const float* __restrict__ b2,
                                                    float* __restrict__ Cf,
                                                    u16* __restrict__ Cb, int mode) {
    __shared__ u16 Hh[32 * HS];
    __shared__ u16 Hl[32 * HS];
    int tid = threadIdx.x;
    int lane = tid & 63, wave = tid >> 6;
    int m16 = lane & 15, quad = lane >> 4;
    int colBase = wave * 32;

    bf16x8 W1H[2][4], W1L[2][4], W2H[2][4], W2L[2][4];
#pragma unroll
    for (int nt = 0; nt < 2; ++nt) {
        int n = colBase + nt * 16 + m16;
#pragma unroll
        for (int kb = 0; kb < 4; ++kb) {
            int off = n * 128 + kb * 32 + quad * 8;
            W1H[nt][kb] = *(const bf16x8*)(W1 + off);
            W1L[nt][kb] = *(const bf16x8*)(W1 + off + 16384);
            W2H[nt][kb] = *(const bf16x8*)(W2 + off);
            W2L[nt][kb] = *(const bf16x8*)(W2 + off + 16384);
        }
    }
    float b1v[2][4], b2v[2][4];
#pragma unroll
    for (int nt = 0; nt < 2; ++nt)
#pragma unroll
        for (int rg = 0; rg < 4; ++rg) {
            int col = colBase + nt * 16 + quad * 4 + rg;
            b1v[nt][rg] = b1[col];
            b2v[nt][rg] = b2[col];
        }

    f32x4 z = {0.f, 0.f, 0.f, 0.f};
    int within = (quad & 1) * 8;     // fragment offset within a 16-col slice

    for (int t0 = blockIdx.x * 2; t0 < TILES; t0 += 2 * GRID_MLP) {
        // ---- load act fragments for both tiles (sliced layout) ----
        bf16x8 aH[2][4], aL[2][4];
#pragma unroll
        for (int p = 0; p < 2; ++p) {
            size_t rowOff = (size_t)((t0 + p) * 16 + m16) * 16 + within;
#pragma unroll
            for (int kb = 0; kb < 4; ++kb) {
                size_t base = (size_t)(kb * 2 + (quad >> 1)) * SSTRIDE + rowOff;
                aH[p][kb] = *(const bf16x8*)(Ah + base);
                aL[p][kb] = *(const bf16x8*)(Al + base);
            }
        }

        f32x4 acc[2][2];
        acc[0][0] = z; acc[0][1] = z; acc[1][0] = z; acc[1][1] = z;

        // ---- pass 1: W1 x act ----
#pragma unroll
        for (int kb = 0; kb < 4; ++kb) {
#pragma unroll
            for (int p = 0; p < 2; ++p) {
                acc[p][0] = MFMA(W1H[0][kb], aH[p][kb], acc[p][0]);
                acc[p][1] = MFMA(W1H[1][kb], aH[p][kb], acc[p][1]);
                acc[p][0] = MFMA(W1H[0][kb], aL[p][kb], acc[p][0]);
                acc[p][1] = MFMA(W1H[1][kb], aL[p][kb], acc[p][1]);
                acc[p][0] = MFMA(W1L[0][kb], aH[p][kb], acc[p][0]);
                acc[p][1] = MFMA(W1L[1][kb], aH[p][kb], acc[p][1]);
            }
        }

        __syncthreads();

        // ---- epilogue 1: bias+relu+split -> LDS ----
#pragma unroll
        for (int p = 0; p < 2; ++p) {
#pragma unroll
            for (int nt = 0; nt < 2; ++nt) {
                ushort4 hv, lv;
#pragma unroll
                for (int rg = 0; rg < 4; ++rg) {
                    float v = fmaxf(acc[p][nt][rg] + b1v[nt][rg], 0.f);
                    u16 hi = f2bf(v);
                    ((u16*)&hv)[rg] = hi;
                    ((u16*)&lv)[rg] = f2bf(v - bf2f(hi));
                }
                int off = (p * 16 + m16) * HS + colBase + nt * 16 + quad * 4;
                *(ushort4*)&Hh[off] = hv;
                *(ushort4*)&Hl[off] = lv;
            }
        }
        __syncthreads();

        // ---- pass 2: W2 x H ----
        acc[0][0] = z; acc[0][1] = z; acc[1][0] = z; acc[1][1] = z;
#pragma unroll
        for (int kb = 0; kb < 4; ++kb) {
#pragma unroll
            for (int p = 0; p < 2; ++p) {
                int off = (p * 16 + m16) * HS + kb * 32 + quad * 8;
                bf16x8 hH = *(const bf16x8*)(&Hh[off]);
                bf16x8 hL = *(const bf16x8*)(&Hl[off]);
                acc[p][0] = MFMA(W2H[0][kb], hH, acc[p][0]);
                acc[p][1] = MFMA(W2H[1][kb], hH, acc[p][1]);
                acc[p][0] = MFMA(W2H[0][kb], hL, acc[p][0]);
                acc[p][1] = MFMA(W2H[1][kb], hL, acc[p][1]);
                acc[p][0] = MFMA(W2L[0][kb], hH, acc[p][0]);
                acc[p][1] = MFMA(W2L[1][kb], hH, acc[p][1]);
            }
        }

        // ---- epilogue 2: bias (+relu) -> global ----
#pragma unroll
        for (int p = 0; p < 2; ++p) {
            size_t row = (size_t)((t0 + p) * 16 + m16);
#pragma unroll
            for (int nt = 0; nt < 2; ++nt) {
                if (mode) {
                    ushort4 o;
#pragma unroll
                    for (int rg = 0; rg < 4; ++rg)
                        ((u16*)&o)[rg] = f2bf(fmaxf(acc[p][nt][rg] + b2v[nt][rg], 0.f));
                    // sliced write: slice = wave*2+nt, within = quad*4
                    *(ushort4*)(Cb + (size_t)(wave * 2 + nt) * SSTRIDE + row * 16 + quad * 4) = o;
                } else {
                    int col = colBase + nt * 16 + quad * 4;
                    float4 o;
                    o.x = acc[p][nt][0] + b2v[nt][0];
                    o.y = acc[p][nt][1] + b2v[nt][1];
                    o.z = acc[p][nt][2] + b2v[nt][2];
                    o.w = acc[p][nt][3] + b2v[nt][3];
                    *(float4*)(Cf + row * 128 + col) = o;
                }
            }
        }
    }
}

// ===========================================================================
// pool stage 1: segment-boundary flush into sums (batch sorted)
// ===========================================================================
__global__ __launch_bounds__(256) void psum_kernel(const float* __restrict__ h,
                                                   const int* __restrict__ batch,
                                                   float* __restrict__ sums) {
    __shared__ int sBatch[128];
    int blk = blockIdx.x, t = threadIdx.x;
    int n0 = blk * 128;
    int nEnd = min(n0 + 128, N_NODES);
    if (t < 128 && n0 + t < N_NODES) sBatch[t] = batch[n0 + t];
    __syncthreads();

    int j = t & 127;
    int half = t >> 7;
    int s = n0 + half * 64;
    int e = min(s + 64, nEnd);

    float acc = 0.f;
    int cur = -1;
    for (int n = s; n < e; ++n) {
        int g = sBatch[n - n0];
        if (g != cur) {
            if (cur >= 0) atomicAdd(&sums[cur * 128 + j], acc);
            cur = g;
            acc = 0.f;
        }
        acc += h[(size_t)n * 128 + j];
    }
    if (cur >= 0) atomicAdd(&sums[cur * 128 + j], acc);
}

// pool stage 2: counts by binary search, divide.
__global__ __launch_bounds__(128) void pdiv_kernel(const float* __restrict__ sums,
                                                   const int* __restrict__ batch,
                                                   float* __restrict__ out) {
    __shared__ int sB[2];
    int g = blockIdx.x;
    if (threadIdx.x < 2) {
        int target = g + threadIdx.x;
        int lo = 0, hi = N_NODES;
        while (lo < hi) {
            int m = (lo + hi) >> 1;
            if (batch[m] < target) lo = m + 1; else hi = m;
        }
        sB[threadIdx.x] = lo;
    }
    __syncthreads();
    float cnt = (float)(sB[1] - sB[0]);
    out[g * 128 + threadIdx.x] = sums[g * 128 + threadIdx.x] / fmaxf(cnt, 1.f);
}

// ===========================================================================
extern "C" void kernel_launch(void* const* d_in, const int* in_sizes, int n_in,
                              void* d_out, int out_size, void* d_ws, size_t ws_size,
                              hipStream_t stream) {
    const float* x     = (const float*)d_in[0];
    const int*   ei    = (const int*)d_in[1];
    const int*   batch = (const int*)d_in[2];
    const int*   eSrc  = ei;
    const int*   eDst  = ei + N_EDGES;

    const float* W1[3] = {(const float*)d_in[3], (const float*)d_in[7],  (const float*)d_in[11]};
    const float* b1[3] = {(const float*)d_in[4], (const float*)d_in[8],  (const float*)d_in[12]};
    const float* W2[3] = {(const float*)d_in[5], (const float*)d_in[9],  (const float*)d_in[13]};
    const float* b2[3] = {(const float*)d_in[6], (const float*)d_in[10], (const float*)d_in[14]};

    // workspace layout
    float* P2 = (float*)d_ws;                          // [N_PAD,128] fp32 (layer-2 out)
    u16*   hb = (u16*)(P2 + (size_t)N_PAD * DIM);      // bf16 hi plane (sliced)
    u16*   Ah = hb + (size_t)N_PAD * DIM;              // agg hi plane (sliced)
    u16*   Al = Ah + (size_t)N_PAD * DIM;              // agg lo plane (sliced)
    u16*   Wb = Al + (size_t)N_PAD * DIM;              // 6 x 32768 u16
    int*   row_ptr = (int*)(Wb + 6 * 32768);           // N_NODES + 8
    u32*   cursorB = (u32*)(row_ptr + N_NODES + 8);    // 128
    int*   csr     = (int*)(cursorB + 128);            // N_EDGES
    float* sums    = (float*)(csr + N_EDGES);          // [128,128]
    u32*   pairs   = (u32*)P2;                         // aliases P2 (disjoint lifetime)

    // ---- CSR build ----
    hipMemsetAsync(cursorB, 0, 128 * sizeof(u32), stream);
    bucket1_kernel<<<(N_EDGES + 1023) / 1024, 256, 0, stream>>>(eSrc, eDst, cursorB, pairs);
    bucket2_kernel<<<NBKT, 1024, 0, stream>>>(cursorB, pairs, row_ptr, csr);

    // ---- x -> bf16 sliced plane, W prep, zero pool sums ----
    xprep_kernel<<<(N_NODES * 32 + 255) / 256, 256, 0, stream>>>(x, hb);
    WPrepArgs wp;
    for (int l = 0; l < 3; ++l) {
        wp.w[2 * l]       = W1[l];
        wp.w[2 * l + 1]   = W2[l];
        wp.buf[2 * l]     = Wb + (size_t)(2 * l) * 32768;
        wp.buf[2 * l + 1] = Wb + (size_t)(2 * l + 1) * 32768;
    }
    wprep_kernel<<<dim3(64, 6), 256, 0, stream>>>(wp);
    hipMemsetAsync(sums, 0, N_GRAPHS * DIM * sizeof(float), stream);

    for (int l = 0; l < 3; ++l) {
        agg_kernel<<<AGG_BPS * 8, 256, 0, stream>>>(hb, row_ptr, csr, Ah, Al);
        fused_mlp<<<GRID_MLP, 256, 0, stream>>>(Ah, Al,
                                                Wb + (size_t)(2 * l) * 32768, b1[l],
                                                Wb + (size_t)(2 * l + 1) * 32768, b2[l],
                                                P2, hb, (l < 2) ? 1 : 0);
    }
    psum_kernel<<<POOL_BLKS, 256, 0, stream>>>(P2, batch, sums);
    pdiv_kernel<<<N_GRAPHS, 128, 0, stream>>>(sums, batch, (float*)d_out);
}

// Round 11
// 731.800 us; speedup vs baseline: 1.3756x; 1.3756x over previous
//
#include <hip/hip_runtime.h>
#include <hip/hip_bf16.h>

#define N_NODES 100000
#define N_PAD   100032          // 1563 * 64
#define N_EDGES 1600000
#define DIM 128
#define N_GRAPHS 128
#define NBKT 98                 // ceil(100000/1024)
#define BSTRIDE 18432           // bucket capacity (mean 16384, +16 sigma)
#define TILES (N_PAD / 16)      // 6252 row-tiles of 16 (even)
#define GRID_MLP 1024
#define POOL_BLKS ((N_NODES + 127) / 128)   // 782

typedef unsigned short u16;
typedef unsigned int u32;
typedef __attribute__((ext_vector_type(8))) short bf16x8;
typedef __attribute__((ext_vector_type(4))) float f32x4;

#define MFMA(A, B, C) __builtin_amdgcn_mfma_f32_16x16x32_bf16(A, B, C, 0, 0, 0)

__device__ __forceinline__ u16 f2bf(float x) {
    u32 u = __float_as_uint(x);
    u = (u + 0x7FFFu + ((u >> 16) & 1u)) >> 16;
    return (u16)u;
}
__device__ __forceinline__ float bf2f(u16 u) {
    return __uint_as_float(((u32)u) << 16);
}

// ===========================================================================
// bucket phase 1: append packed (dstLocal<<22 | src) to coarse buckets.
// ===========================================================================
__global__ __launch_bounds__(256) void bucket1_kernel(const int* __restrict__ src,
                                                      const int* __restrict__ dst,
                                                      u32* __restrict__ cursorB,
                                                      u32* __restrict__ pairs) {
    __shared__ int lh[NBKT];
    __shared__ u32 lbase[NBKT];
    int t = threadIdx.x;
    if (t < NBKT) lh[t] = 0;
    __syncthreads();
    int e0 = blockIdx.x * 1024;
    int d[4], s[4], rk[4], bk[4];
#pragma unroll
    for (int k = 0; k < 4; ++k) {
        int e = e0 + t + k * 256;
        if (e < N_EDGES) {
            d[k] = dst[e];
            s[k] = src[e];
            bk[k] = d[k] >> 10;
            rk[k] = atomicAdd(&lh[bk[k]], 1);
        }
    }
    __syncthreads();
    if (t < NBKT) lbase[t] = atomicAdd(&cursorB[t], (u32)lh[t]) + (u32)(t * BSTRIDE);
    __syncthreads();
#pragma unroll
    for (int k = 0; k < 4; ++k) {
        int e = e0 + t + k * 256;
        if (e < N_EDGES) {
            u32 pos = lbase[bk[k]] + (u32)rk[k];
            pairs[pos] = ((u32)(d[k] & 1023) << 22) | (u32)s[k];
        }
    }
}

// ===========================================================================
// bucket phase 2: per-bucket hist + scan -> row_ptr, then scatter into csr.
// ===========================================================================
__global__ __launch_bounds__(1024) void bucket2_kernel(const u32* __restrict__ cursorB,
                                                       const u32* __restrict__ pairs,
                                                       int* __restrict__ row_ptr,
                                                       int* __restrict__ csr) {
    __shared__ int lh[1024];
    __shared__ int rc[1024];
    __shared__ int bs[128];
    int b = blockIdx.x, t = threadIdx.x;

    if (t < 128) bs[t] = (t < NBKT) ? (int)cursorB[t] : 0;
    __syncthreads();
    for (int off = 1; off < 128; off <<= 1) {
        int v = (t < 128 && t >= off) ? bs[t - off] : 0;
        __syncthreads();
        if (t < 128) bs[t] += v;
        __syncthreads();
    }
    int cnt = (int)cursorB[b];
    int bbase = (b == 0) ? 0 : bs[b - 1];

    lh[t] = 0;
    __syncthreads();
    const u32* pb = pairs + (size_t)b * BSTRIDE;
    for (int i = t; i < cnt; i += 1024) atomicAdd(&lh[pb[i] >> 22], 1);
    __syncthreads();

    int own = lh[t];
    for (int off = 1; off < 1024; off <<= 1) {
        int v = (t >= off) ? lh[t - off] : 0;
        __syncthreads();
        lh[t] += v;
        __syncthreads();
    }
    int excl = lh[t] - own;
    int node = b * 1024 + t;
    if (node < N_NODES) row_ptr[node] = bbase + excl;
    if (b == 0 && t == 0) row_ptr[N_NODES] = N_EDGES;
    rc[t] = bbase + excl;
    __syncthreads();

    for (int i = t; i < cnt; i += 1024) {
        u32 p = pb[i];
        int pos = atomicAdd(&rc[p >> 22], 1);
        csr[pos] = (int)(p & 0x3FFFFFu);
    }
}

// ===========================================================================
// x -> bf16 hi plane (row-major), once per launch
// ===========================================================================
__global__ __launch_bounds__(256) void xprep_kernel(const float* __restrict__ x,
                                                    u16* __restrict__ hb) {
    int i = blockIdx.x * 256 + threadIdx.x;
    if (i < N_NODES * 32) {
        float4 v = ((const float4*)x)[i];
        ushort4 o;
        o.x = f2bf(v.x); o.y = f2bf(v.y); o.z = f2bf(v.z); o.w = f2bf(v.w);
        ((ushort4*)hb)[i] = o;
    }
}

// ===========================================================================
// W prep: fp32 W[k][n] -> WT planes: hi at [n*128+k], lo at [n*128+k + 16384]
// ===========================================================================
struct WPrepArgs {
    const float* w[6];
    u16* buf[6];
};
__global__ __launch_bounds__(256) void wprep_kernel(WPrepArgs p) {
    int m = blockIdx.y;
    int idx = blockIdx.x * 256 + threadIdx.x;   // n*128 + k
    int n = idx >> 7, k = idx & 127;
    float v = p.w[m][k * 128 + n];
    u16 hi = f2bf(v);
    p.buf[m][idx] = hi;
    p.buf[m][idx + 16384] = f2bf(v - bf2f(hi));
}

// ===========================================================================
// fused layer: gather (GIN sum) -> LDS A-tile -> MLP (W in regs, MFMA).
// 32 rows (2 MFMA tiles) per chunk, grid-strided. hbIn ping-pongs with output.
// gather (memory) of one resident block overlaps MFMA of the other.
// ===========================================================================
#define HS 136
__global__ __launch_bounds__(256, 2) void fused_layer(const u16* __restrict__ hbIn,
                                                      const int* __restrict__ rp,
                                                      const int* __restrict__ csr,
                                                      const u16* __restrict__ W1,
                                                      const float* __restrict__ b1,
                                                      const u16* __restrict__ W2,
                                                      const float* __restrict__ b2,
                                                      float* __restrict__ Cf,
                                                      u16* __restrict__ Cb, int mode) {
    __shared__ u16 Ahs[32 * HS];
    __shared__ u16 Als[32 * HS];
    __shared__ u16 Hh[32 * HS];
    __shared__ u16 Hl[32 * HS];
    int tid = threadIdx.x;
    int lane = tid & 63, wave = tid >> 6;
    int m16 = lane & 15, quad = lane >> 4;
    int colBase = wave * 32;
    int hw = tid >> 5;          // half-wave 0..7 (gather)
    int gl = tid & 31;          // gather lane

    // ---- loop-invariant W fragments in registers ----
    bf16x8 W1H[2][4], W1L[2][4], W2H[2][4], W2L[2][4];
#pragma unroll
    for (int nt = 0; nt < 2; ++nt) {
        int n = colBase + nt * 16 + m16;
#pragma unroll
        for (int kb = 0; kb < 4; ++kb) {
            int off = n * 128 + kb * 32 + quad * 8;
            W1H[nt][kb] = *(const bf16x8*)(W1 + off);
            W1L[nt][kb] = *(const bf16x8*)(W1 + off + 16384);
            W2H[nt][kb] = *(const bf16x8*)(W2 + off);
            W2L[nt][kb] = *(const bf16x8*)(W2 + off + 16384);
        }
    }
    float b1v[2][4], b2v[2][4];
#pragma unroll
    for (int nt = 0; nt < 2; ++nt)
#pragma unroll
        for (int rg = 0; rg < 4; ++rg) {
            int col = colBase + nt * 16 + quad * 4 + rg;
            b1v[nt][rg] = b1[col];
            b2v[nt][rg] = b2[col];
        }

    f32x4 z = {0.f, 0.f, 0.f, 0.f};
    const ushort4* h4 = (const ushort4*)hbIn;

    for (int t0 = blockIdx.x * 2; t0 < TILES; t0 += 2 * GRID_MLP) {
        int base = t0 * 16;   // 32 rows: base .. base+31

        // ===== gather phase: half-wave per node, 4 nodes per half-wave =====
#pragma unroll
        for (int k = 0; k < 4; ++k) {
            int r = hw + 8 * k;          // LDS row 0..31
            int node = base + r;
            float a0 = 0.f, a1 = 0.f, a2 = 0.f, a3 = 0.f;
            if (node < N_NODES) {
                ushort4 sv = h4[(size_t)node * 32 + gl];
                a0 = bf2f(sv.x); a1 = bf2f(sv.y); a2 = bf2f(sv.z); a3 = bf2f(sv.w);
                int s = rp[node], e = rp[node + 1];
                int i = s;
                for (; i + 8 <= e; i += 8) {
                    ushort4 v0 = h4[(size_t)csr[i + 0] * 32 + gl];
                    ushort4 v1 = h4[(size_t)csr[i + 1] * 32 + gl];
                    ushort4 v2 = h4[(size_t)csr[i + 2] * 32 + gl];
                    ushort4 v3 = h4[(size_t)csr[i + 3] * 32 + gl];
                    ushort4 v4 = h4[(size_t)csr[i + 4] * 32 + gl];
                    ushort4 v5 = h4[(size_t)csr[i + 5] * 32 + gl];
                    ushort4 v6 = h4[(size_t)csr[i + 6] * 32 + gl];
                    ushort4 v7 = h4[(size_t)csr[i + 7] * 32 + gl];
                    a0 += ((bf2f(v0.x) + bf2f(v1.x)) + (bf2f(v2.x) + bf2f(v3.x))) +
                          ((bf2f(v4.x) + bf2f(v5.x)) + (bf2f(v6.x) + bf2f(v7.x)));
                    a1 += ((bf2f(v0.y) + bf2f(v1.y)) + (bf2f(v2.y) + bf2f(v3.y))) +
                          ((bf2f(v4.y) + bf2f(v5.y)) + (bf2f(v6.y) + bf2f(v7.y)));
                    a2 += ((bf2f(v0.z) + bf2f(v1.z)) + (bf2f(v2.z) + bf2f(v3.z))) +
                          ((bf2f(v4.z) + bf2f(v5.z)) + (bf2f(v6.z) + bf2f(v7.z)));
                    a3 += ((bf2f(v0.w) + bf2f(v1.w)) + (bf2f(v2.w) + bf2f(v3.w))) +
                          ((bf2f(v4.w) + bf2f(v5.w)) + (bf2f(v6.w) + bf2f(v7.w)));
                }
                for (; i < e; ++i) {
                    ushort4 v = h4[(size_t)csr[i] * 32 + gl];
                    a0 += bf2f(v.x); a1 += bf2f(v.y); a2 += bf2f(v.z); a3 += bf2f(v.w);
                }
            }
            ushort4 hv, lv;
            hv.x = f2bf(a0); lv.x = f2bf(a0 - bf2f(hv.x));
            hv.y = f2bf(a1); lv.y = f2bf(a1 - bf2f(hv.y));
            hv.z = f2bf(a2); lv.z = f2bf(a2 - bf2f(hv.z));
            hv.w = f2bf(a3); lv.w = f2bf(a3 - bf2f(hv.w));
            *(ushort4*)&Ahs[r * HS + gl * 4] = hv;
            *(ushort4*)&Als[r * HS + gl * 4] = lv;
        }
        __syncthreads();   // A-tile ready (also: prev iter fully complete)

        // ===== pass 1: W1 x A (A frags read from LDS in-loop) =====
        f32x4 acc[2][2];
        acc[0][0] = z; acc[0][1] = z; acc[1][0] = z; acc[1][1] = z;
#pragma unroll
        for (int kb = 0; kb < 4; ++kb) {
#pragma unroll
            for (int p = 0; p < 2; ++p) {
                int off = (p * 16 + m16) * HS + kb * 32 + quad * 8;
                bf16x8 aH = *(const bf16x8*)(&Ahs[off]);
                bf16x8 aL = *(const bf16x8*)(&Als[off]);
                acc[p][0] = MFMA(W1H[0][kb], aH, acc[p][0]);
                acc[p][1] = MFMA(W1H[1][kb], aH, acc[p][1]);
                acc[p][0] = MFMA(W1H[0][kb], aL, acc[p][0]);
                acc[p][1] = MFMA(W1H[1][kb], aL, acc[p][1]);
                acc[p][0] = MFMA(W1L[0][kb], aH, acc[p][0]);
                acc[p][1] = MFMA(W1L[1][kb], aH, acc[p][1]);
            }
        }

        // ===== epilogue 1: bias+relu+split -> H (different LDS arrays) =====
#pragma unroll
        for (int p = 0; p < 2; ++p) {
#pragma unroll
            for (int nt = 0; nt < 2; ++nt) {
                ushort4 hv, lv;
#pragma unroll
                for (int rg = 0; rg < 4; ++rg) {
                    float v = fmaxf(acc[p][nt][rg] + b1v[nt][rg], 0.f);
                    u16 hi = f2bf(v);
                    ((u16*)&hv)[rg] = hi;
                    ((u16*)&lv)[rg] = f2bf(v - bf2f(hi));
                }
                int off = (p * 16 + m16) * HS + colBase + nt * 16 + quad * 4;
                *(ushort4*)&Hh[off] = hv;
                *(ushort4*)&Hl[off] = lv;
            }
        }
        __syncthreads();   // H visible

        // ===== pass 2: W2 x H =====
        acc[0][0] = z; acc[0][1] = z; acc[1][0] = z; acc[1][1] = z;
#pragma unroll
        for (int kb = 0; kb < 4; ++kb) {
#pragma unroll
            for (int p = 0; p < 2; ++p) {
                int off = (p * 16 + m16) * HS + kb * 32 + quad * 8;
                bf16x8 hH = *(const bf16x8*)(&Hh[off]);
                bf16x8 hL = *(const bf16x8*)(&Hl[off]);
                acc[p][0] = MFMA(W2H[0][kb], hH, acc[p][0]);
                acc[p][1] = MFMA(W2H[1][kb], hH, acc[p][1]);
                acc[p][0] = MFMA(W2H[0][kb], hL, acc[p][0]);
                acc[p][1] = MFMA(W2H[1][kb], hL, acc[p][1]);
                acc[p][0] = MFMA(W2L[0][kb], hH, acc[p][0]);
                acc[p][1] = MFMA(W2L[1][kb], hH, acc[p][1]);
            }
        }

        // ===== epilogue 2: bias (+relu) -> global =====
#pragma unroll
        for (int p = 0; p < 2; ++p) {
            size_t row = (size_t)(base + p * 16 + m16);
#pragma unroll
            for (int nt = 0; nt < 2; ++nt) {
                int col = colBase + nt * 16 + quad * 4;
                if (mode) {
                    ushort4 o;
#pragma unroll
                    for (int rg = 0; rg < 4; ++rg)
                        ((u16*)&o)[rg] = f2bf(fmaxf(acc[p][nt][rg] + b2v[nt][rg], 0.f));
                    *(ushort4*)(Cb + row * 128 + col) = o;
                } else {
                    float4 o;
                    o.x = acc[p][nt][0] + b2v[nt][0];
                    o.y = acc[p][nt][1] + b2v[nt][1];
                    o.z = acc[p][nt][2] + b2v[nt][2];
                    o.w = acc[p][nt][3] + b2v[nt][3];
                    *(float4*)(Cf + row * 128 + col) = o;
                }
            }
        }
        // no trailing sync needed: next iteration's gather-writes are fenced
        // by the __syncthreads() after the gather phase (full barrier since
        // every thread completed this iteration before passing it)
    }
}

// ===========================================================================
// pool stage 1: segment-boundary flush into sums (batch sorted)
// ===========================================================================
__global__ __launch_bounds__(256) void psum_kernel(const float* __restrict__ h,
                                                   const int* __restrict__ batch,
                                                   float* __restrict__ sums) {
    __shared__ int sBatch[128];
    int blk = blockIdx.x, t = threadIdx.x;
    int n0 = blk * 128;
    int nEnd = min(n0 + 128, N_NODES);
    if (t < 128 && n0 + t < N_NODES) sBatch[t] = batch[n0 + t];
    __syncthreads();

    int j = t & 127;
    int half = t >> 7;
    int s = n0 + half * 64;
    int e = min(s + 64, nEnd);

    float acc = 0.f;
    int cur = -1;
    for (int n = s; n < e; ++n) {
        int g = sBatch[n - n0];
        if (g != cur) {
            if (cur >= 0) atomicAdd(&sums[cur * 128 + j], acc);
            cur = g;
            acc = 0.f;
        }
        acc += h[(size_t)n * 128 + j];
    }
    if (cur >= 0) atomicAdd(&sums[cur * 128 + j], acc);
}

// pool stage 2: counts by binary search, divide.
__global__ __launch_bounds__(128) void pdiv_kernel(const float* __restrict__ sums,
                                                   const int* __restrict__ batch,
                                                   float* __restrict__ out) {
    __shared__ int sB[2];
    int g = blockIdx.x;
    if (threadIdx.x < 2) {
        int target = g + threadIdx.x;
        int lo = 0, hi = N_NODES;
        while (lo < hi) {
            int m = (lo + hi) >> 1;
            if (batch[m] < target) lo = m + 1; else hi = m;
        }
        sB[threadIdx.x] = lo;
    }
    __syncthreads();
    float cnt = (float)(sB[1] - sB[0]);
    out[g * 128 + threadIdx.x] = sums[g * 128 + threadIdx.x] / fmaxf(cnt, 1.f);
}

// ===========================================================================
extern "C" void kernel_launch(void* const* d_in, const int* in_sizes, int n_in,
                              void* d_out, int out_size, void* d_ws, size_t ws_size,
                              hipStream_t stream) {
    const float* x     = (const float*)d_in[0];
    const int*   ei    = (const int*)d_in[1];
    const int*   batch = (const int*)d_in[2];
    const int*   eSrc  = ei;
    const int*   eDst  = ei + N_EDGES;

    const float* W1[3] = {(const float*)d_in[3], (const float*)d_in[7],  (const float*)d_in[11]};
    const float* b1[3] = {(const float*)d_in[4], (const float*)d_in[8],  (const float*)d_in[12]};
    const float* W2[3] = {(const float*)d_in[5], (const float*)d_in[9],  (const float*)d_in[13]};
    const float* b2[3] = {(const float*)d_in[6], (const float*)d_in[10], (const float*)d_in[14]};

    // workspace layout
    float* P2 = (float*)d_ws;                          // [N_PAD,128] fp32 (layer-2 out)
    u16*   hb0 = (u16*)(P2 + (size_t)N_PAD * DIM);     // bf16 plane A
    u16*   hb1 = hb0 + (size_t)N_PAD * DIM;            // bf16 plane B
    u16*   Wb  = hb1 + (size_t)N_PAD * DIM;            // 6 x 32768 u16
    int*   row_ptr = (int*)(Wb + 6 * 32768);           // N_NODES + 8
    u32*   cursorB = (u32*)(row_ptr + N_NODES + 8);    // 128
    int*   csr     = (int*)(cursorB + 128);            // N_EDGES
    float* sums    = (float*)(csr + N_EDGES);          // [128,128]
    u32*   pairs   = (u32*)P2;                         // aliases P2 (disjoint lifetime)

    // ---- CSR build ----
    hipMemsetAsync(cursorB, 0, 128 * sizeof(u32), stream);
    bucket1_kernel<<<(N_EDGES + 1023) / 1024, 256, 0, stream>>>(eSrc, eDst, cursorB, pairs);
    bucket2_kernel<<<NBKT, 1024, 0, stream>>>(cursorB, pairs, row_ptr, csr);

    // ---- x -> bf16 plane, W prep, zero pool sums ----
    xprep_kernel<<<(N_NODES * 32 + 255) / 256, 256, 0, stream>>>(x, hb0);
    WPrepArgs wp;
    for (int l = 0; l < 3; ++l) {
        wp.w[2 * l]       = W1[l];
        wp.w[2 * l + 1]   = W2[l];
        wp.buf[2 * l]     = Wb + (size_t)(2 * l) * 32768;
        wp.buf[2 * l + 1] = Wb + (size_t)(2 * l + 1) * 32768;
    }
    wprep_kernel<<<dim3(64, 6), 256, 0, stream>>>(wp);
    hipMemsetAsync(sums, 0, N_GRAPHS * DIM * sizeof(float), stream);

    // ---- 3 fused layers (ping-pong planes) ----
    const u16* in[3]  = {hb0, hb1, hb0};
    u16*       outB[3] = {hb1, hb0, nullptr};
    for (int l = 0; l < 3; ++l) {
        fused_layer<<<GRID_MLP, 256, 0, stream>>>(in[l], row_ptr, csr,
                                                  Wb + (size_t)(2 * l) * 32768, b1[l],
                                                  Wb + (size_t)(2 * l + 1) * 32768, b2[l],
                                                  P2, outB[l], (l < 2) ? 1 : 0);
    }
    psum_kernel<<<POOL_BLKS, 256, 0, stream>>>(P2, batch, sums);
    pdiv_kernel<<<N_GRAPHS, 128, 0, stream>>>(sums, batch, (float*)d_out);
}

// Round 12
// 587.453 us; speedup vs baseline: 1.7136x; 1.2457x over previous
//
#include <hip/hip_runtime.h>
#include <hip/hip_bf16.h>

#define N_NODES 100000
#define N_PAD   100032          // 1563 * 64
#define N_EDGES 1600000
#define DIM 128
#define N_GRAPHS 128
#define NBKT 98                 // ceil(100000/1024)
#define BSTRIDE 18432           // bucket capacity (mean 16384, +16 sigma)
#define TILES (N_PAD / 16)      // 6252 row-tiles of 16 (even)
#define GRID_MLP 1024
#define POOL_BLKS ((N_NODES + 127) / 128)   // 782

typedef unsigned short u16;
typedef unsigned int u32;
typedef __attribute__((ext_vector_type(8))) short bf16x8;
typedef __attribute__((ext_vector_type(4))) float f32x4;

#define MFMA(A, B, C) __builtin_amdgcn_mfma_f32_16x16x32_bf16(A, B, C, 0, 0, 0)

__device__ __forceinline__ u16 f2bf(float x) {
    u32 u = __float_as_uint(x);
    u = (u + 0x7FFFu + ((u >> 16) & 1u)) >> 16;
    return (u16)u;
}
__device__ __forceinline__ float bf2f(u16 u) {
    return __uint_as_float(((u32)u) << 16);
}

// ===========================================================================
// bucket phase 1: append packed (dstLocal<<22 | src) to coarse buckets.
// pairs written non-temporally (scattered partial lines; don't allocate L2).
// ===========================================================================
__global__ __launch_bounds__(256) void bucket1_kernel(const int* __restrict__ src,
                                                      const int* __restrict__ dst,
                                                      u32* __restrict__ cursorB,
                                                      u32* __restrict__ pairs) {
    __shared__ int lh[NBKT];
    __shared__ u32 lbase[NBKT];
    int t = threadIdx.x;
    if (t < NBKT) lh[t] = 0;
    __syncthreads();
    int e0 = blockIdx.x * 1024;
    int d[4], s[4], rk[4], bk[4];
#pragma unroll
    for (int k = 0; k < 4; ++k) {
        int e = e0 + t + k * 256;
        if (e < N_EDGES) {
            d[k] = dst[e];
            s[k] = src[e];
            bk[k] = d[k] >> 10;
            rk[k] = atomicAdd(&lh[bk[k]], 1);
        }
    }
    __syncthreads();
    if (t < NBKT) lbase[t] = atomicAdd(&cursorB[t], (u32)lh[t]) + (u32)(t * BSTRIDE);
    __syncthreads();
#pragma unroll
    for (int k = 0; k < 4; ++k) {
        int e = e0 + t + k * 256;
        if (e < N_EDGES) {
            u32 pos = lbase[bk[k]] + (u32)rk[k];
            __builtin_nontemporal_store(((u32)(d[k] & 1023) << 22) | (u32)s[k],
                                        pairs + pos);
        }
    }
}

// ===========================================================================
// bucket phase 2: per-bucket hist + scan -> row_ptr, then scatter into csr.
// ===========================================================================
__global__ __launch_bounds__(1024) void bucket2_kernel(const u32* __restrict__ cursorB,
                                                       const u32* __restrict__ pairs,
                                                       int* __restrict__ row_ptr,
                                                       int* __restrict__ csr) {
    __shared__ int lh[1024];
    __shared__ int rc[1024];
    __shared__ int bs[128];
    int b = blockIdx.x, t = threadIdx.x;

    if (t < 128) bs[t] = (t < NBKT) ? (int)cursorB[t] : 0;
    __syncthreads();
    for (int off = 1; off < 128; off <<= 1) {
        int v = (t < 128 && t >= off) ? bs[t - off] : 0;
        __syncthreads();
        if (t < 128) bs[t] += v;
        __syncthreads();
    }
    int cnt = (int)cursorB[b];
    int bbase = (b == 0) ? 0 : bs[b - 1];

    lh[t] = 0;
    __syncthreads();
    const u32* pb = pairs + (size_t)b * BSTRIDE;
    for (int i = t; i < cnt; i += 1024) atomicAdd(&lh[__builtin_nontemporal_load(pb + i) >> 22], 1);
    __syncthreads();

    int own = lh[t];
    for (int off = 1; off < 1024; off <<= 1) {
        int v = (t >= off) ? lh[t - off] : 0;
        __syncthreads();
        lh[t] += v;
        __syncthreads();
    }
    int excl = lh[t] - own;
    int node = b * 1024 + t;
    if (node < N_NODES) row_ptr[node] = bbase + excl;
    if (b == 0 && t == 0) row_ptr[N_NODES] = N_EDGES;
    rc[t] = bbase + excl;
    __syncthreads();

    for (int i = t; i < cnt; i += 1024) {
        u32 p = __builtin_nontemporal_load(pb + i);
        int pos = atomicAdd(&rc[p >> 22], 1);
        csr[pos] = (int)(p & 0x3FFFFFu);
    }
}

// ===========================================================================
// x -> bf16 hi plane (row-major), once per launch
// ===========================================================================
__global__ __launch_bounds__(256) void xprep_kernel(const float* __restrict__ x,
                                                    u16* __restrict__ hb) {
    int i = blockIdx.x * 256 + threadIdx.x;
    if (i < N_NODES * 32) {
        float4 v = ((const float4*)x)[i];
        ushort4 o;
        o.x = f2bf(v.x); o.y = f2bf(v.y); o.z = f2bf(v.z); o.w = f2bf(v.w);
        ((ushort4*)hb)[i] = o;
    }
}

// ===========================================================================
// aggregation (R7 form, proven 66.5 µs): half-wave per node, ushort4/lane
// ===========================================================================
__global__ __launch_bounds__(256) void agg_kernel(const u16* __restrict__ hb,
                                                  const int* __restrict__ rp,
                                                  const int* __restrict__ csr,
                                                  u16* __restrict__ Ah,
                                                  u16* __restrict__ Al) {
    int node = (blockIdx.x * 256 + threadIdx.x) >> 5;
    int l = threadIdx.x & 31;
    if (node >= N_NODES) return;
    const ushort4* h4 = (const ushort4*)hb;
    ushort4 sv = h4[(size_t)node * 32 + l];
    float a0 = bf2f(sv.x), a1 = bf2f(sv.y), a2 = bf2f(sv.z), a3 = bf2f(sv.w);
    int s = rp[node], e = rp[node + 1];
    int i = s;
    for (; i + 8 <= e; i += 8) {
        ushort4 v0 = h4[(size_t)csr[i + 0] * 32 + l];
        ushort4 v1 = h4[(size_t)csr[i + 1] * 32 + l];
        ushort4 v2 = h4[(size_t)csr[i + 2] * 32 + l];
        ushort4 v3 = h4[(size_t)csr[i + 3] * 32 + l];
        ushort4 v4 = h4[(size_t)csr[i + 4] * 32 + l];
        ushort4 v5 = h4[(size_t)csr[i + 5] * 32 + l];
        ushort4 v6 = h4[(size_t)csr[i + 6] * 32 + l];
        ushort4 v7 = h4[(size_t)csr[i + 7] * 32 + l];
        a0 += ((bf2f(v0.x) + bf2f(v1.x)) + (bf2f(v2.x) + bf2f(v3.x))) +
              ((bf2f(v4.x) + bf2f(v5.x)) + (bf2f(v6.x) + bf2f(v7.x)));
        a1 += ((bf2f(v0.y) + bf2f(v1.y)) + (bf2f(v2.y) + bf2f(v3.y))) +
              ((bf2f(v4.y) + bf2f(v5.y)) + (bf2f(v6.y) + bf2f(v7.y)));
        a2 += ((bf2f(v0.z) + bf2f(v1.z)) + (bf2f(v2.z) + bf2f(v3.z))) +
              ((bf2f(v4.z) + bf2f(v5.z)) + (bf2f(v6.z) + bf2f(v7.z)));
        a3 += ((bf2f(v0.w) + bf2f(v1.w)) + (bf2f(v2.w) + bf2f(v3.w))) +
              ((bf2f(v4.w) + bf2f(v5.w)) + (bf2f(v6.w) + bf2f(v7.w)));
    }
    for (; i < e; ++i) {
        ushort4 v = h4[(size_t)csr[i] * 32 + l];
        a0 += bf2f(v.x); a1 += bf2f(v.y); a2 += bf2f(v.z); a3 += bf2f(v.w);
    }
    ushort4 hv, lv;
    hv.x = f2bf(a0); lv.x = f2bf(a0 - bf2f(hv.x));
    hv.y = f2bf(a1); lv.y = f2bf(a1 - bf2f(hv.y));
    hv.z = f2bf(a2); lv.z = f2bf(a2 - bf2f(hv.z));
    hv.w = f2bf(a3); lv.w = f2bf(a3 - bf2f(hv.w));
    *(ushort4*)(Ah + (size_t)node * 128 + l * 4) = hv;
    *(ushort4*)(Al + (size_t)node * 128 + l * 4) = lv;
}

// ===========================================================================
// W prep: fp32 W[k][n] -> WT planes: hi at [n*128+k], lo at [n*128+k + 16384]
// ===========================================================================
struct WPrepArgs {
    const float* w[6];
    u16* buf[6];
};
__global__ __launch_bounds__(256) void wprep_kernel(WPrepArgs p) {
    int m = blockIdx.y;
    int idx = blockIdx.x * 256 + threadIdx.x;   // n*128 + k
    int n = idx >> 7, k = idx & 127;
    float v = p.w[m][k * 128 + n];
    u16 hi = f2bf(v);
    p.buf[m][idx] = hi;
    p.buf[m][idx + 16384] = f2bf(v - bf2f(hi));
}

// ===========================================================================
// fused MLP, W-in-registers, 2 row-tiles/iter. Next-iter A-fragment loads are
// issued at the START of pass 2 into the then-dead aH/aL registers: the path
// pass2 -> epilogue2 -> loop-top -> pass1 has NO __syncthreads, so the loads
// are never drained by a barrier and complete during ~24 MFMAs + epilogue.
// ===========================================================================
#define HS 136
__global__ __launch_bounds__(256, 2) void fused_mlp(const u16* __restrict__ Ah,
                                                    const u16* __restrict__ Al,
                                                    const u16* __restrict__ W1,
                                                    const float* __restrict__ b1,
                                                    const u16* __restrict__ W2,
                                                    const float* __restrict__ b2,
                                                    float* __restrict__ Cf,
                                                    u16* __restrict__ Cb, int mode) {
    __shared__ u16 Hh[32 * HS];
    __shared__ u16 Hl[32 * HS];
    int tid = threadIdx.x;
    int lane = tid & 63, wave = tid >> 6;
    int m16 = lane & 15, quad = lane >> 4;
    int colBase = wave * 32;

    bf16x8 W1H[2][4], W1L[2][4], W2H[2][4], W2L[2][4];
#pragma unroll
    for (int nt = 0; nt < 2; ++nt) {
        int n = colBase + nt * 16 + m16;
#pragma unroll
        for (int kb = 0; kb < 4; ++kb) {
            int off = n * 128 + kb * 32 + quad * 8;
            W1H[nt][kb] = *(const bf16x8*)(W1 + off);
            W1L[nt][kb] = *(const bf16x8*)(W1 + off + 16384);
            W2H[nt][kb] = *(const bf16x8*)(W2 + off);
            W2L[nt][kb] = *(const bf16x8*)(W2 + off + 16384);
        }
    }
    float b1v[2][4], b2v[2][4];
#pragma unroll
    for (int nt = 0; nt < 2; ++nt)
#pragma unroll
        for (int rg = 0; rg < 4; ++rg) {
            int col = colBase + nt * 16 + quad * 4 + rg;
            b1v[nt][rg] = b1[col];
            b2v[nt][rg] = b2[col];
        }

    f32x4 z = {0.f, 0.f, 0.f, 0.f};
    bf16x8 aH[2][4], aL[2][4];

    int t0 = blockIdx.x * 2;
    if (t0 < TILES) {
#pragma unroll
        for (int p = 0; p < 2; ++p) {
            const u16* ah = Ah + (size_t)((t0 + p) * 16 + m16) * 128 + quad * 8;
            const u16* al = Al + (size_t)((t0 + p) * 16 + m16) * 128 + quad * 8;
#pragma unroll
            for (int kb = 0; kb < 4; ++kb) {
                aH[p][kb] = *(const bf16x8*)(ah + kb * 32);
                aL[p][kb] = *(const bf16x8*)(al + kb * 32);
            }
        }
    }

    for (; t0 < TILES; t0 += 2 * GRID_MLP) {
        f32x4 acc[2][2];
        acc[0][0] = z; acc[0][1] = z; acc[1][0] = z; acc[1][1] = z;

        // ---- pass 1: W1 x act ----
#pragma unroll
        for (int kb = 0; kb < 4; ++kb) {
#pragma unroll
            for (int p = 0; p < 2; ++p) {
                acc[p][0] = MFMA(W1H[0][kb], aH[p][kb], acc[p][0]);
                acc[p][1] = MFMA(W1H[1][kb], aH[p][kb], acc[p][1]);
                acc[p][0] = MFMA(W1H[0][kb], aL[p][kb], acc[p][0]);
                acc[p][1] = MFMA(W1H[1][kb], aL[p][kb], acc[p][1]);
                acc[p][0] = MFMA(W1L[0][kb], aH[p][kb], acc[p][0]);
                acc[p][1] = MFMA(W1L[1][kb], aH[p][kb], acc[p][1]);
            }
        }

        __syncthreads();   // prev iteration's pass-2 H reads complete

        // ---- epilogue 1: bias+relu+split -> LDS (ushort4 = ds_write_b64) ----
#pragma unroll
        for (int p = 0; p < 2; ++p) {
#pragma unroll
            for (int nt = 0; nt < 2; ++nt) {
                ushort4 hv, lv;
#pragma unroll
                for (int rg = 0; rg < 4; ++rg) {
                    float v = fmaxf(acc[p][nt][rg] + b1v[nt][rg], 0.f);
                    u16 hi = f2bf(v);
                    ((u16*)&hv)[rg] = hi;
                    ((u16*)&lv)[rg] = f2bf(v - bf2f(hi));
                }
                int off = (p * 16 + m16) * HS + colBase + nt * 16 + quad * 4;
                *(ushort4*)&Hh[off] = hv;
                *(ushort4*)&Hl[off] = lv;
            }
        }
        __syncthreads();   // H visible to all waves

        // ---- prefetch next iter's A frags into now-dead aH/aL ----
        int nt0 = t0 + 2 * GRID_MLP;
        if (nt0 < TILES) {
#pragma unroll
            for (int p = 0; p < 2; ++p) {
                const u16* ah = Ah + (size_t)((nt0 + p) * 16 + m16) * 128 + quad * 8;
                const u16* al = Al + (size_t)((nt0 + p) * 16 + m16) * 128 + quad * 8;
#pragma unroll
                for (int kb = 0; kb < 4; ++kb) {
                    aH[p][kb] = *(const bf16x8*)(ah + kb * 32);
                    aL[p][kb] = *(const bf16x8*)(al + kb * 32);
                }
            }
        }

        // ---- pass 2: W2 x H ----
        f32x4 acc2[2][2];
        acc2[0][0] = z; acc2[0][1] = z; acc2[1][0] = z; acc2[1][1] = z;
#pragma unroll
        for (int kb = 0; kb < 4; ++kb) {
#pragma unroll
            for (int p = 0; p < 2; ++p) {
                int off = (p * 16 + m16) * HS + kb * 32 + quad * 8;
                bf16x8 hH = *(const bf16x8*)(&Hh[off]);
                bf16x8 hL = *(const bf16x8*)(&Hl[off]);
                acc2[p][0] = MFMA(W2H[0][kb], hH, acc2[p][0]);
                acc2[p][1] = MFMA(W2H[1][kb], hH, acc2[p][1]);
                acc2[p][0] = MFMA(W2H[0][kb], hL, acc2[p][0]);
                acc2[p][1] = MFMA(W2H[1][kb], hL, acc2[p][1]);
                acc2[p][0] = MFMA(W2L[0][kb], hH, acc2[p][0]);
                acc2[p][1] = MFMA(W2L[1][kb], hH, acc2[p][1]);
            }
        }

        // ---- epilogue 2: bias (+relu) -> global, vectorized ----
#pragma unroll
        for (int p = 0; p < 2; ++p) {
            size_t row = (size_t)(t0 + p) * 16 + m16;
#pragma unroll
            for (int nt = 0; nt < 2; ++nt) {
                int col = colBase + nt * 16 + quad * 4;
                if (mode) {
                    ushort4 o;
#pragma unroll
                    for (int rg = 0; rg < 4; ++rg)
                        ((u16*)&o)[rg] = f2bf(fmaxf(acc2[p][nt][rg] + b2v[nt][rg], 0.f));
                    *(ushort4*)(Cb + row * 128 + col) = o;
                } else {
                    float4 o;
                    o.x = acc2[p][nt][0] + b2v[nt][0];
                    o.y = acc2[p][nt][1] + b2v[nt][1];
                    o.z = acc2[p][nt][2] + b2v[nt][2];
                    o.w = acc2[p][nt][3] + b2v[nt][3];
                    *(float4*)(Cf + row * 128 + col) = o;
                }
            }
        }
    }
}

// ===========================================================================
// pool stage 1: segment-boundary flush into sums (batch sorted)
// ===========================================================================
__global__ __launch_bounds__(256) void psum_kernel(const float* __restrict__ h,
                                                   const int* __restrict__ batch,
                                                   float* __restrict__ sums) {
    __shared__ int sBatch[128];
    int blk = blockIdx.x, t = threadIdx.x;
    int n0 = blk * 128;
    int nEnd = min(n0 + 128, N_NODES);
    if (t < 128 && n0 + t < N_NODES) sBatch[t] = batch[n0 + t];
    __syncthreads();

    int j = t & 127;
    int half = t >> 7;
    int s = n0 + half * 64;
    int e = min(s + 64, nEnd);

    float acc = 0.f;
    int cur = -1;
    for (int n = s; n < e; ++n) {
        int g = sBatch[n - n0];
        if (g != cur) {
            if (cur >= 0) atomicAdd(&sums[cur * 128 + j], acc);
            cur = g;
            acc = 0.f;
        }
        acc += h[(size_t)n * 128 + j];
    }
    if (cur >= 0) atomicAdd(&sums[cur * 128 + j], acc);
}

// pool stage 2: counts by binary search, divide.
__global__ __launch_bounds__(128) void pdiv_kernel(const float* __restrict__ sums,
                                                   const int* __restrict__ batch,
                                                   float* __restrict__ out) {
    __shared__ int sB[2];
    int g = blockIdx.x;
    if (threadIdx.x < 2) {
        int target = g + threadIdx.x;
        int lo = 0, hi = N_NODES;
        while (lo < hi) {
            int m = (lo + hi) >> 1;
            if (batch[m] < target) lo = m + 1; else hi = m;
        }
        sB[threadIdx.x] = lo;
    }
    __syncthreads();
    float cnt = (float)(sB[1] - sB[0]);
    out[g * 128 + threadIdx.x] = sums[g * 128 + threadIdx.x] / fmaxf(cnt, 1.f);
}

// ===========================================================================
extern "C" void kernel_launch(void* const* d_in, const int* in_sizes, int n_in,
                              void* d_out, int out_size, void* d_ws, size_t ws_size,
                              hipStream_t stream) {
    const float* x     = (const float*)d_in[0];
    const int*   ei    = (const int*)d_in[1];
    const int*   batch = (const int*)d_in[2];
    const int*   eSrc  = ei;
    const int*   eDst  = ei + N_EDGES;

    const float* W1[3] = {(const float*)d_in[3], (const float*)d_in[7],  (const float*)d_in[11]};
    const float* b1[3] = {(const float*)d_in[4], (const float*)d_in[8],  (const float*)d_in[12]};
    const float* W2[3] = {(const float*)d_in[5], (const float*)d_in[9],  (const float*)d_in[13]};
    const float* b2[3] = {(const float*)d_in[6], (const float*)d_in[10], (const float*)d_in[14]};

    // workspace layout
    float* P2 = (float*)d_ws;                          // [N_PAD,128] fp32 (layer-2 out)
    u16*   hb = (u16*)(P2 + (size_t)N_PAD * DIM);      // bf16 hi plane
    u16*   Ah = hb + (size_t)N_PAD * DIM;              // agg hi plane
    u16*   Al = Ah + (size_t)N_PAD * DIM;              // agg lo plane
    u16*   Wb = Al + (size_t)N_PAD * DIM;              // 6 x 32768 u16
    int*   row_ptr = (int*)(Wb + 6 * 32768);           // N_NODES + 8
    u32*   cursorB = (u32*)(row_ptr + N_NODES + 8);    // 128
    int*   csr     = (int*)(cursorB + 128);            // N_EDGES
    float* sums    = (float*)(csr + N_EDGES);          // [128,128]
    u32*   pairs   = (u32*)P2;                         // aliases P2 (disjoint lifetime)

    // ---- CSR build ----
    hipMemsetAsync(cursorB, 0, 128 * sizeof(u32), stream);
    bucket1_kernel<<<(N_EDGES + 1023) / 1024, 256, 0, stream>>>(eSrc, eDst, cursorB, pairs);
    bucket2_kernel<<<NBKT, 1024, 0, stream>>>(cursorB, pairs, row_ptr, csr);

    // ---- x -> bf16 plane, W prep, zero pool sums ----
    xprep_kernel<<<(N_NODES * 32 + 255) / 256, 256, 0, stream>>>(x, hb);
    WPrepArgs wp;
    for (int l = 0; l < 3; ++l) {
        wp.w[2 * l]       = W1[l];
        wp.w[2 * l + 1]   = W2[l];
        wp.buf[2 * l]     = Wb + (size_t)(2 * l) * 32768;
        wp.buf[2 * l + 1] = Wb + (size_t)(2 * l + 1) * 32768;
    }
    wprep_kernel<<<dim3(64, 6), 256, 0, stream>>>(wp);
    hipMemsetAsync(sums, 0, N_GRAPHS * DIM * sizeof(float), stream);

    const int aggGrid = (N_NODES * 32 + 255) / 256;

    for (int l = 0; l < 3; ++l) {
        agg_kernel<<<aggGrid, 256, 0, stream>>>(hb, row_ptr, csr, Ah, Al);
        fused_mlp<<<GRID_MLP, 256, 0, stream>>>(Ah, Al,
                                                Wb + (size_t)(2 * l) * 32768, b1[l],
                                                Wb + (size_t)(2 * l + 1) * 32768, b2[l],
                                                P2, hb, (l < 2) ? 1 : 0);
    }
    psum_kernel<<<POOL_BLKS, 256, 0, stream>>>(P2, batch, sums);
    pdiv_kernel<<<N_GRAPHS, 128, 0, stream>>>(sums, batch, (float*)d_out);
}

// Round 13
// 532.063 us; speedup vs baseline: 1.8920x; 1.1041x over previous
//
#include <hip/hip_runtime.h>
#include <hip/hip_bf16.h>

#define N_NODES 100000
#define N_PAD   100032          // 1563 * 64
#define N_EDGES 1600000
#define DIM 128
#define N_GRAPHS 128
#define NBKT 98                 // ceil(100000/1024)
#define BSTRIDE 18432           // bucket capacity (mean 16384, +16 sigma)
#define TILES (N_PAD / 16)      // 6252 row-tiles of 16 (even)
#define GRID_MLP 1024
#define POOL_BLKS ((N_NODES + 127) / 128)   // 782
#define B1_BATCH 4096
#define B1_GRID ((N_EDGES + B1_BATCH - 1) / B1_BATCH)   // 391

typedef unsigned short u16;
typedef unsigned int u32;
typedef __attribute__((ext_vector_type(8))) short bf16x8;
typedef __attribute__((ext_vector_type(4))) float f32x4;

#define MFMA(A, B, C) __builtin_amdgcn_mfma_f32_16x16x32_bf16(A, B, C, 0, 0, 0)

__device__ __forceinline__ u16 f2bf(float x) {
    u32 u = __float_as_uint(x);
    u = (u + 0x7FFFu + ((u >> 16) & 1u)) >> 16;
    return (u16)u;
}
__device__ __forceinline__ float bf2f(u16 u) {
    return __uint_as_float(((u32)u) << 16);
}

// ===========================================================================
// bucket phase 1: append packed (dstLocal<<22 | src) to coarse buckets.
// 4096 edges/block (16/thread): per-(block,bucket) segments ~167B -> mostly
// full L2 lines. Cached stores (L2 write-combines concurrent same-segment
// lanes; NT store here measured +20us regression in R12).
// ===========================================================================
__global__ __launch_bounds__(256) void bucket1_kernel(const int* __restrict__ src,
                                                      const int* __restrict__ dst,
                                                      u32* __restrict__ cursorB,
                                                      u32* __restrict__ pairs) {
    __shared__ int lh[NBKT];
    __shared__ u32 lbase[NBKT];
    int t = threadIdx.x;
    if (t < NBKT) lh[t] = 0;
    __syncthreads();
    int e0 = blockIdx.x * B1_BATCH;
    int d[16], s[16], rk[16];
#pragma unroll
    for (int k = 0; k < 16; ++k) {
        int e = e0 + t + k * 256;
        if (e < N_EDGES) {
            d[k] = dst[e];
            s[k] = src[e];
            rk[k] = atomicAdd(&lh[d[k] >> 10], 1);
        }
    }
    __syncthreads();
    if (t < NBKT) lbase[t] = atomicAdd(&cursorB[t], (u32)lh[t]) + (u32)(t * BSTRIDE);
    __syncthreads();
#pragma unroll
    for (int k = 0; k < 16; ++k) {
        int e = e0 + t + k * 256;
        if (e < N_EDGES) {
            u32 pos = lbase[d[k] >> 10] + (u32)rk[k];
            pairs[pos] = ((u32)(d[k] & 1023) << 22) | (u32)s[k];
        }
    }
}

// ===========================================================================
// bucket phase 2: per-bucket hist + scan -> row_ptr, then scatter into csr.
// ===========================================================================
__global__ __launch_bounds__(1024) void bucket2_kernel(const u32* __restrict__ cursorB,
                                                       const u32* __restrict__ pairs,
                                                       int* __restrict__ row_ptr,
                                                       int* __restrict__ csr) {
    __shared__ int lh[1024];
    __shared__ int rc[1024];
    __shared__ int bs[128];
    int b = blockIdx.x, t = threadIdx.x;

    if (t < 128) bs[t] = (t < NBKT) ? (int)cursorB[t] : 0;
    __syncthreads();
    for (int off = 1; off < 128; off <<= 1) {
        int v = (t < 128 && t >= off) ? bs[t - off] : 0;
        __syncthreads();
        if (t < 128) bs[t] += v;
        __syncthreads();
    }
    int cnt = (int)cursorB[b];
    int bbase = (b == 0) ? 0 : bs[b - 1];

    lh[t] = 0;
    __syncthreads();
    const u32* pb = pairs + (size_t)b * BSTRIDE;
    for (int i = t; i < cnt; i += 1024) atomicAdd(&lh[__builtin_nontemporal_load(pb + i) >> 22], 1);
    __syncthreads();

    int own = lh[t];
    for (int off = 1; off < 1024; off <<= 1) {
        int v = (t >= off) ? lh[t - off] : 0;
        __syncthreads();
        lh[t] += v;
        __syncthreads();
    }
    int excl = lh[t] - own;
    int node = b * 1024 + t;
    if (node < N_NODES) row_ptr[node] = bbase + excl;
    if (b == 0 && t == 0) row_ptr[N_NODES] = N_EDGES;
    rc[t] = bbase + excl;
    __syncthreads();

    for (int i = t; i < cnt; i += 1024) {
        u32 p = __builtin_nontemporal_load(pb + i);
        int pos = atomicAdd(&rc[p >> 22], 1);
        csr[pos] = (int)(p & 0x3FFFFFu);
    }
}

// ===========================================================================
// x -> bf16 hi plane (row-major), once per launch
// ===========================================================================
__global__ __launch_bounds__(256) void xprep_kernel(const float* __restrict__ x,
                                                    u16* __restrict__ hb) {
    int i = blockIdx.x * 256 + threadIdx.x;
    if (i < N_NODES * 32) {
        float4 v = ((const float4*)x)[i];
        ushort4 o;
        o.x = f2bf(v.x); o.y = f2bf(v.y); o.z = f2bf(v.z); o.w = f2bf(v.w);
        ((ushort4*)hb)[i] = o;
    }
}

// ===========================================================================
// aggregation (R7 form, proven 66.5 µs): half-wave per node, ushort4/lane
// ===========================================================================
__global__ __launch_bounds__(256) void agg_kernel(const u16* __restrict__ hb,
                                                  const int* __restrict__ rp,
                                                  const int* __restrict__ csr,
                                                  u16* __restrict__ Ah,
                                                  u16* __restrict__ Al) {
    int node = (blockIdx.x * 256 + threadIdx.x) >> 5;
    int l = threadIdx.x & 31;
    if (node >= N_NODES) return;
    const ushort4* h4 = (const ushort4*)hb;
    ushort4 sv = h4[(size_t)node * 32 + l];
    float a0 = bf2f(sv.x), a1 = bf2f(sv.y), a2 = bf2f(sv.z), a3 = bf2f(sv.w);
    int s = rp[node], e = rp[node + 1];
    int i = s;
    for (; i + 8 <= e; i += 8) {
        ushort4 v0 = h4[(size_t)csr[i + 0] * 32 + l];
        ushort4 v1 = h4[(size_t)csr[i + 1] * 32 + l];
        ushort4 v2 = h4[(size_t)csr[i + 2] * 32 + l];
        ushort4 v3 = h4[(size_t)csr[i + 3] * 32 + l];
        ushort4 v4 = h4[(size_t)csr[i + 4] * 32 + l];
        ushort4 v5 = h4[(size_t)csr[i + 5] * 32 + l];
        ushort4 v6 = h4[(size_t)csr[i + 6] * 32 + l];
        ushort4 v7 = h4[(size_t)csr[i + 7] * 32 + l];
        a0 += ((bf2f(v0.x) + bf2f(v1.x)) + (bf2f(v2.x) + bf2f(v3.x))) +
              ((bf2f(v4.x) + bf2f(v5.x)) + (bf2f(v6.x) + bf2f(v7.x)));
        a1 += ((bf2f(v0.y) + bf2f(v1.y)) + (bf2f(v2.y) + bf2f(v3.y))) +
              ((bf2f(v4.y) + bf2f(v5.y)) + (bf2f(v6.y) + bf2f(v7.y)));
        a2 += ((bf2f(v0.z) + bf2f(v1.z)) + (bf2f(v2.z) + bf2f(v3.z))) +
              ((bf2f(v4.z) + bf2f(v5.z)) + (bf2f(v6.z) + bf2f(v7.z)));
        a3 += ((bf2f(v0.w) + bf2f(v1.w)) + (bf2f(v2.w) + bf2f(v3.w))) +
              ((bf2f(v4.w) + bf2f(v5.w)) + (bf2f(v6.w) + bf2f(v7.w)));
    }
    for (; i < e; ++i) {
        ushort4 v = h4[(size_t)csr[i] * 32 + l];
        a0 += bf2f(v.x); a1 += bf2f(v.y); a2 += bf2f(v.z); a3 += bf2f(v.w);
    }
    ushort4 hv, lv;
    hv.x = f2bf(a0); lv.x = f2bf(a0 - bf2f(hv.x));
    hv.y = f2bf(a1); lv.y = f2bf(a1 - bf2f(hv.y));
    hv.z = f2bf(a2); lv.z = f2bf(a2 - bf2f(hv.z));
    hv.w = f2bf(a3); lv.w = f2bf(a3 - bf2f(hv.w));
    *(ushort4*)(Ah + (size_t)node * 128 + l * 4) = hv;
    *(ushort4*)(Al + (size_t)node * 128 + l * 4) = lv;
}

// ===========================================================================
// W prep: fp32 W[k][n] -> WT planes: hi at [n*128+k], lo at [n*128+k + 16384]
// ===========================================================================
struct WPrepArgs {
    const float* w[6];
    u16* buf[6];
};
__global__ __launch_bounds__(256) void wprep_kernel(WPrepArgs p) {
    int m = blockIdx.y;
    int idx = blockIdx.x * 256 + threadIdx.x;   // n*128 + k
    int n = idx >> 7, k = idx & 127;
    float v = p.w[m][k * 128 + n];
    u16 hi = f2bf(v);
    p.buf[m][idx] = hi;
    p.buf[m][idx + 16384] = f2bf(v - bf2f(hi));
}

// ===========================================================================
// fused MLP, W-in-registers, 2 row-tiles/iter, barrier-free A prefetch
// issued between the barriers (never drained before use).
// ===========================================================================
#define HS 136
__global__ __launch_bounds__(256, 2) void fused_mlp(const u16* __restrict__ Ah,
                                                    const u16* __restrict__ Al,
                                                    const u16* __restrict__ W1,
                                                    const float* __restrict__ b1,
                                                    const u16* __restrict__ W2,
                                                    const float* __restrict__ b2,
                                                    float* __restrict__ Cf,
                                                    u16* __restrict__ Cb, int mode) {
    __shared__ u16 Hh[32 * HS];
    __shared__ u16 Hl[32 * HS];
    int tid = threadIdx.x;
    int lane = tid & 63, wave = tid >> 6;
    int m16 = lane & 15, quad = lane >> 4;
    int colBase = wave * 32;

    bf16x8 W1H[2][4], W1L[2][4], W2H[2][4], W2L[2][4];
#pragma unroll
    for (int nt = 0; nt < 2; ++nt) {
        int n = colBase + nt * 16 + m16;
#pragma unroll
        for (int kb = 0; kb < 4; ++kb) {
            int off = n * 128 + kb * 32 + quad * 8;
            W1H[nt][kb] = *(const bf16x8*)(W1 + off);
            W1L[nt][kb] = *(const bf16x8*)(W1 + off + 16384);
            W2H[nt][kb] = *(const bf16x8*)(W2 + off);
            W2L[nt][kb] = *(const bf16x8*)(W2 + off + 16384);
        }
    }
    float b1v[2][4], b2v[2][4];
#pragma unroll
    for (int nt = 0; nt < 2; ++nt)
#pragma unroll
        for (int rg = 0; rg < 4; ++rg) {
            int col = colBase + nt * 16 + quad * 4 + rg;
            b1v[nt][rg] = b1[col];
            b2v[nt][rg] = b2[col];
        }

    f32x4 z = {0.f, 0.f, 0.f, 0.f};
    bf16x8 aH[2][4], aL[2][4];

    int t0 = blockIdx.x * 2;
    if (t0 < TILES) {
#pragma unroll
        for (int p = 0; p < 2; ++p) {
            const u16* ah = Ah + (size_t)((t0 + p) * 16 + m16) * 128 + quad * 8;
            const u16* al = Al + (size_t)((t0 + p) * 16 + m16) * 128 + quad * 8;
#pragma unroll
            for (int kb = 0; kb < 4; ++kb) {
                aH[p][kb] = *(const bf16x8*)(ah + kb * 32);
                aL[p][kb] = *(const bf16x8*)(al + kb * 32);
            }
        }
    }

    for (; t0 < TILES; t0 += 2 * GRID_MLP) {
        f32x4 acc[2][2];
        acc[0][0] = z; acc[0][1] = z; acc[1][0] = z; acc[1][1] = z;

        // ---- pass 1: W1 x act ----
#pragma unroll
        for (int kb = 0; kb < 4; ++kb) {
#pragma unroll
            for (int p = 0; p < 2; ++p) {
                acc[p][0] = MFMA(W1H[0][kb], aH[p][kb], acc[p][0]);
                acc[p][1] = MFMA(W1H[1][kb], aH[p][kb], acc[p][1]);
                acc[p][0] = MFMA(W1H[0][kb], aL[p][kb], acc[p][0]);
                acc[p][1] = MFMA(W1H[1][kb], aL[p][kb], acc[p][1]);
                acc[p][0] = MFMA(W1L[0][kb], aH[p][kb], acc[p][0]);
                acc[p][1] = MFMA(W1L[1][kb], aH[p][kb], acc[p][1]);
            }
        }

        __syncthreads();   // prev iteration's pass-2 H reads complete

        // ---- epilogue 1: bias+relu+split -> LDS ----
#pragma unroll
        for (int p = 0; p < 2; ++p) {
#pragma unroll
            for (int nt = 0; nt < 2; ++nt) {
                ushort4 hv, lv;
#pragma unroll
                for (int rg = 0; rg < 4; ++rg) {
                    float v = fmaxf(acc[p][nt][rg] + b1v[nt][rg], 0.f);
                    u16 hi = f2bf(v);
                    ((u16*)&hv)[rg] = hi;
                    ((u16*)&lv)[rg] = f2bf(v - bf2f(hi));
                }
                int off = (p * 16 + m16) * HS + colBase + nt * 16 + quad * 4;
                *(ushort4*)&Hh[off] = hv;
                *(ushort4*)&Hl[off] = lv;
            }
        }
        __syncthreads();   // H visible to all waves

        // ---- prefetch next iter's A frags into now-dead aH/aL ----
        int nt0 = t0 + 2 * GRID_MLP;
        if (nt0 < TILES) {
#pragma unroll
            for (int p = 0; p < 2; ++p) {
                const u16* ah = Ah + (size_t)((nt0 + p) * 16 + m16) * 128 + quad * 8;
                const u16* al = Al + (size_t)((nt0 + p) * 16 + m16) * 128 + quad * 8;
#pragma unroll
                for (int kb = 0; kb < 4; ++kb) {
                    aH[p][kb] = *(const bf16x8*)(ah + kb * 32);
                    aL[p][kb] = *(const bf16x8*)(al + kb * 32);
                }
            }
        }

        // ---- pass 2: W2 x H ----
        f32x4 acc2[2][2];
        acc2[0][0] = z; acc2[0][1] = z; acc2[1][0] = z; acc2[1][1] = z;
#pragma unroll
        for (int kb = 0; kb < 4; ++kb) {
#pragma unroll
            for (int p = 0; p < 2; ++p) {
                int off = (p * 16 + m16) * HS + kb * 32 + quad * 8;
                bf16x8 hH = *(const bf16x8*)(&Hh[off]);
                bf16x8 hL = *(const bf16x8*)(&Hl[off]);
                acc2[p][0] = MFMA(W2H[0][kb], hH, acc2[p][0]);
                acc2[p][1] = MFMA(W2H[1][kb], hH, acc2[p][1]);
                acc2[p][0] = MFMA(W2H[0][kb], hL, acc2[p][0]);
                acc2[p][1] = MFMA(W2H[1][kb], hL, acc2[p][1]);
                acc2[p][0] = MFMA(W2L[0][kb], hH, acc2[p][0]);
                acc2[p][1] = MFMA(W2L[1][kb], hH, acc2[p][1]);
            }
        }

        // ---- epilogue 2: bias (+relu) -> global, vectorized ----
#pragma unroll
        for (int p = 0; p < 2; ++p) {
            size_t row = (size_t)(t0 + p) * 16 + m16;
#pragma unroll
            for (int nt = 0; nt < 2; ++nt) {
                int col = colBase + nt * 16 + quad * 4;
                if (mode) {
                    ushort4 o;
#pragma unroll
                    for (int rg = 0; rg < 4; ++rg)
                        ((u16*)&o)[rg] = f2bf(fmaxf(acc2[p][nt][rg] + b2v[nt][rg], 0.f));
                    *(ushort4*)(Cb + row * 128 + col) = o;
                } else {
                    float4 o;
                    o.x = acc2[p][nt][0] + b2v[nt][0];
                    o.y = acc2[p][nt][1] + b2v[nt][1];
                    o.z = acc2[p][nt][2] + b2v[nt][2];
                    o.w = acc2[p][nt][3] + b2v[nt][3];
                    *(float4*)(Cf + row * 128 + col) = o;
                }
            }
        }
    }
}

// ===========================================================================
// pool stage 1: segment-boundary flush into sums (batch sorted)
// ===========================================================================
__global__ __launch_bounds__(256) void psum_kernel(const float* __restrict__ h,
                                                   const int* __restrict__ batch,
                                                   float* __restrict__ sums) {
    __shared__ int sBatch[128];
    int blk = blockIdx.x, t = threadIdx.x;
    int n0 = blk * 128;
    int nEnd = min(n0 + 128, N_NODES);
    if (t < 128 && n0 + t < N_NODES) sBatch[t] = batch[n0 + t];
    __syncthreads();

    int j = t & 127;
    int half = t >> 7;
    int s = n0 + half * 64;
    int e = min(s + 64, nEnd);

    float acc = 0.f;
    int cur = -1;
    for (int n = s; n < e; ++n) {
        int g = sBatch[n - n0];
        if (g != cur) {
            if (cur >= 0) atomicAdd(&sums[cur * 128 + j], acc);
            cur = g;
            acc = 0.f;
        }
        acc += h[(size_t)n * 128 + j];
    }
    if (cur >= 0) atomicAdd(&sums[cur * 128 + j], acc);
}

// pool stage 2: counts by binary search, divide.
__global__ __launch_bounds__(128) void pdiv_kernel(const float* __restrict__ sums,
                                                   const int* __restrict__ batch,
                                                   float* __restrict__ out) {
    __shared__ int sB[2];
    int g = blockIdx.x;
    if (threadIdx.x < 2) {
        int target = g + threadIdx.x;
        int lo = 0, hi = N_NODES;
        while (lo < hi) {
            int m = (lo + hi) >> 1;
            if (batch[m] < target) lo = m + 1; else hi = m;
        }
        sB[threadIdx.x] = lo;
    }
    __syncthreads();
    float cnt = (float)(sB[1] - sB[0]);
    out[g * 128 + threadIdx.x] = sums[g * 128 + threadIdx.x] / fmaxf(cnt, 1.f);
}

// ===========================================================================
extern "C" void kernel_launch(void* const* d_in, const int* in_sizes, int n_in,
                              void* d_out, int out_size, void* d_ws, size_t ws_size,
                              hipStream_t stream) {
    const float* x     = (const float*)d_in[0];
    const int*   ei    = (const int*)d_in[1];
    const int*   batch = (const int*)d_in[2];
    const int*   eSrc  = ei;
    const int*   eDst  = ei + N_EDGES;

    const float* W1[3] = {(const float*)d_in[3], (const float*)d_in[7],  (const float*)d_in[11]};
    const float* b1[3] = {(const float*)d_in[4], (const float*)d_in[8],  (const float*)d_in[12]};
    const float* W2[3] = {(const float*)d_in[5], (const float*)d_in[9],  (const float*)d_in[13]};
    const float* b2[3] = {(const float*)d_in[6], (const float*)d_in[10], (const float*)d_in[14]};

    // workspace layout
    float* P2 = (float*)d_ws;                          // [N_PAD,128] fp32 (layer-2 out)
    u16*   hb = (u16*)(P2 + (size_t)N_PAD * DIM);      // bf16 hi plane
    u16*   Ah = hb + (size_t)N_PAD * DIM;              // agg hi plane
    u16*   Al = Ah + (size_t)N_PAD * DIM;              // agg lo plane
    u16*   Wb = Al + (size_t)N_PAD * DIM;              // 6 x 32768 u16
    int*   row_ptr = (int*)(Wb + 6 * 32768);           // N_NODES + 8
    u32*   cursorB = (u32*)(row_ptr + N_NODES + 8);    // 128
    int*   csr     = (int*)(cursorB + 128);            // N_EDGES
    float* sums    = (float*)(csr + N_EDGES);          // [128,128]
    u32*   pairs   = (u32*)P2;                         // aliases P2 (disjoint lifetime)

    // ---- CSR build ----
    hipMemsetAsync(cursorB, 0, 128 * sizeof(u32), stream);
    bucket1_kernel<<<B1_GRID, 256, 0, stream>>>(eSrc, eDst, cursorB, pairs);
    bucket2_kernel<<<NBKT, 1024, 0, stream>>>(cursorB, pairs, row_ptr, csr);

    // ---- x -> bf16 plane, W prep, zero pool sums ----
    xprep_kernel<<<(N_NODES * 32 + 255) / 256, 256, 0, stream>>>(x, hb);
    WPrepArgs wp;
    for (int l = 0; l < 3; ++l) {
        wp.w[2 * l]       = W1[l];
        wp.w[2 * l + 1]   = W2[l];
        wp.buf[2 * l]     = Wb + (size_t)(2 * l) * 32768;
        wp.buf[2 * l + 1] = Wb + (size_t)(2 * l + 1) * 32768;
    }
    wprep_kernel<<<dim3(64, 6), 256, 0, stream>>>(wp);
    hipMemsetAsync(sums, 0, N_GRAPHS * DIM * sizeof(float), stream);

    const int aggGrid = (N_NODES * 32 + 255) / 256;

    for (int l = 0; l < 3; ++l) {
        agg_kernel<<<aggGrid, 256, 0, stream>>>(hb, row_ptr, csr, Ah, Al);
        fused_mlp<<<GRID_MLP, 256, 0, stream>>>(Ah, Al,
                                                Wb + (size_t)(2 * l) * 32768, b1[l],
                                                Wb + (size_t)(2 * l + 1) * 32768, b2[l],
                                                P2, hb, (l < 2) ? 1 : 0);
    }
    psum_kernel<<<POOL_BLKS, 256, 0, stream>>>(P2, batch, sums);
    pdiv_kernel<<<N_GRAPHS, 128, 0, stream>>>(sums, batch, (float*)d_out);
}

// Round 14
// 514.874 us; speedup vs baseline: 1.9552x; 1.0334x over previous
//
#include <hip/hip_runtime.h>
#include <hip/hip_bf16.h>

#define N_NODES 100000
#define N_PAD   100032          // 1563 * 64
#define N_EDGES 1600000
#define DIM 128
#define N_GRAPHS 128
#define NBKT 98                 // ceil(100000/1024)
#define BSTRIDE 18432           // bucket capacity (mean 16384, +16 sigma)
#define TILES (N_PAD / 16)      // 6252 row-tiles of 16 (divisible by 4)
#define GRID_MLP 1024
#define POOL_BLKS ((N_NODES + 127) / 128)   // 782
#define B1_BATCH 4096
#define B1_GRID ((N_EDGES + B1_BATCH - 1) / B1_BATCH)   // 391

typedef unsigned short u16;
typedef unsigned int u32;
typedef __attribute__((ext_vector_type(8))) short bf16x8;
typedef __attribute__((ext_vector_type(4))) float f32x4;

#define MFMA(A, B, C) __builtin_amdgcn_mfma_f32_16x16x32_bf16(A, B, C, 0, 0, 0)

__device__ __forceinline__ u16 f2bf(float x) {
    u32 u = __float_as_uint(x);
    u = (u + 0x7FFFu + ((u >> 16) & 1u)) >> 16;
    return (u16)u;
}
__device__ __forceinline__ float bf2f(u16 u) {
    return __uint_as_float(((u32)u) << 16);
}

// ===========================================================================
// bucket phase 1: append packed (dstLocal<<22 | src) to coarse buckets.
// 4096 edges/block: per-(block,bucket) segments ~167B (mostly full L2 lines).
// Cached stores (NT store here measured +20us regression in R12).
// ===========================================================================
__global__ __launch_bounds__(256) void bucket1_kernel(const int* __restrict__ src,
                                                      const int* __restrict__ dst,
                                                      u32* __restrict__ cursorB,
                                                      u32* __restrict__ pairs) {
    __shared__ int lh[NBKT];
    __shared__ u32 lbase[NBKT];
    int t = threadIdx.x;
    if (t < NBKT) lh[t] = 0;
    __syncthreads();
    int e0 = blockIdx.x * B1_BATCH;
    int d[16], s[16], rk[16];
#pragma unroll
    for (int k = 0; k < 16; ++k) {
        int e = e0 + t + k * 256;
        if (e < N_EDGES) {
            d[k] = dst[e];
            s[k] = src[e];
            rk[k] = atomicAdd(&lh[d[k] >> 10], 1);
        }
    }
    __syncthreads();
    if (t < NBKT) lbase[t] = atomicAdd(&cursorB[t], (u32)lh[t]) + (u32)(t * BSTRIDE);
    __syncthreads();
#pragma unroll
    for (int k = 0; k < 16; ++k) {
        int e = e0 + t + k * 256;
        if (e < N_EDGES) {
            u32 pos = lbase[d[k] >> 10] + (u32)rk[k];
            pairs[pos] = ((u32)(d[k] & 1023) << 22) | (u32)s[k];
        }
    }
}

// ===========================================================================
// bucket phase 2: per-bucket hist + scan -> row_ptr, then scatter into csr.
// ===========================================================================
__global__ __launch_bounds__(1024) void bucket2_kernel(const u32* __restrict__ cursorB,
                                                       const u32* __restrict__ pairs,
                                                       int* __restrict__ row_ptr,
                                                       int* __restrict__ csr) {
    __shared__ int lh[1024];
    __shared__ int rc[1024];
    __shared__ int bs[128];
    int b = blockIdx.x, t = threadIdx.x;

    if (t < 128) bs[t] = (t < NBKT) ? (int)cursorB[t] : 0;
    __syncthreads();
    for (int off = 1; off < 128; off <<= 1) {
        int v = (t < 128 && t >= off) ? bs[t - off] : 0;
        __syncthreads();
        if (t < 128) bs[t] += v;
        __syncthreads();
    }
    int cnt = (int)cursorB[b];
    int bbase = (b == 0) ? 0 : bs[b - 1];

    lh[t] = 0;
    __syncthreads();
    const u32* pb = pairs + (size_t)b * BSTRIDE;
    for (int i = t; i < cnt; i += 1024) atomicAdd(&lh[__builtin_nontemporal_load(pb + i) >> 22], 1);
    __syncthreads();

    int own = lh[t];
    for (int off = 1; off < 1024; off <<= 1) {
        int v = (t >= off) ? lh[t - off] : 0;
        __syncthreads();
        lh[t] += v;
        __syncthreads();
    }
    int excl = lh[t] - own;
    int node = b * 1024 + t;
    if (node < N_NODES) row_ptr[node] = bbase + excl;
    if (b == 0 && t == 0) row_ptr[N_NODES] = N_EDGES;
    rc[t] = bbase + excl;
    __syncthreads();

    for (int i = t; i < cnt; i += 1024) {
        u32 p = __builtin_nontemporal_load(pb + i);
        int pos = atomicAdd(&rc[p >> 22], 1);
        csr[pos] = (int)(p & 0x3FFFFFu);
    }
}

// ===========================================================================
// x -> bf16 hi plane (row-major), once per launch
// ===========================================================================
__global__ __launch_bounds__(256) void xprep_kernel(const float* __restrict__ x,
                                                    u16* __restrict__ hb) {
    int i = blockIdx.x * 256 + threadIdx.x;
    if (i < N_NODES * 32) {
        float4 v = ((const float4*)x)[i];
        ushort4 o;
        o.x = f2bf(v.x); o.y = f2bf(v.y); o.z = f2bf(v.z); o.w = f2bf(v.w);
        ((ushort4*)hb)[i] = o;
    }
}

// ===========================================================================
// aggregation (R7 loop shape): half-wave per node, ushort4/lane, unroll 8.
// Output: bf16 hi plane only (lo residual dropped -- see R13 precision note:
// input hb is already bf16, so the sum's lo-residual is below input noise).
// ===========================================================================
__global__ __launch_bounds__(256) void agg_kernel(const u16* __restrict__ hb,
                                                  const int* __restrict__ rp,
                                                  const int* __restrict__ csr,
                                                  u16* __restrict__ Ah) {
    int node = (blockIdx.x * 256 + threadIdx.x) >> 5;
    int l = threadIdx.x & 31;
    if (node >= N_NODES) return;
    const ushort4* h4 = (const ushort4*)hb;
    ushort4 sv = h4[(size_t)node * 32 + l];
    float a0 = bf2f(sv.x), a1 = bf2f(sv.y), a2 = bf2f(sv.z), a3 = bf2f(sv.w);
    int s = rp[node], e = rp[node + 1];
    int i = s;
    for (; i + 8 <= e; i += 8) {
        ushort4 v0 = h4[(size_t)csr[i + 0] * 32 + l];
        ushort4 v1 = h4[(size_t)csr[i + 1] * 32 + l];
        ushort4 v2 = h4[(size_t)csr[i + 2] * 32 + l];
        ushort4 v3 = h4[(size_t)csr[i + 3] * 32 + l];
        ushort4 v4 = h4[(size_t)csr[i + 4] * 32 + l];
        ushort4 v5 = h4[(size_t)csr[i + 5] * 32 + l];
        ushort4 v6 = h4[(size_t)csr[i + 6] * 32 + l];
        ushort4 v7 = h4[(size_t)csr[i + 7] * 32 + l];
        a0 += ((bf2f(v0.x) + bf2f(v1.x)) + (bf2f(v2.x) + bf2f(v3.x))) +
              ((bf2f(v4.x) + bf2f(v5.x)) + (bf2f(v6.x) + bf2f(v7.x)));
        a1 += ((bf2f(v0.y) + bf2f(v1.y)) + (bf2f(v2.y) + bf2f(v3.y))) +
              ((bf2f(v4.y) + bf2f(v5.y)) + (bf2f(v6.y) + bf2f(v7.y)));
        a2 += ((bf2f(v0.z) + bf2f(v1.z)) + (bf2f(v2.z) + bf2f(v3.z))) +
              ((bf2f(v4.z) + bf2f(v5.z)) + (bf2f(v6.z) + bf2f(v7.z)));
        a3 += ((bf2f(v0.w) + bf2f(v1.w)) + (bf2f(v2.w) + bf2f(v3.w))) +
              ((bf2f(v4.w) + bf2f(v5.w)) + (bf2f(v6.w) + bf2f(v7.w)));
    }
    for (; i < e; ++i) {
        ushort4 v = h4[(size_t)csr[i] * 32 + l];
        a0 += bf2f(v.x); a1 += bf2f(v.y); a2 += bf2f(v.z); a3 += bf2f(v.w);
    }
    ushort4 hv;
    hv.x = f2bf(a0); hv.y = f2bf(a1); hv.z = f2bf(a2); hv.w = f2bf(a3);
    *(ushort4*)(Ah + (size_t)node * 128 + l * 4) = hv;
}

// ===========================================================================
// W prep: fp32 W[k][n] -> WT planes: hi at [n*128+k], lo at [n*128+k + 16384]
// ===========================================================================
struct WPrepArgs {
    const float* w[6];
    u16* buf[6];
};
__global__ __launch_bounds__(256) void wprep_kernel(WPrepArgs p) {
    int m = blockIdx.y;
    int idx = blockIdx.x * 256 + threadIdx.x;   // n*128 + k
    int n = idx >> 7, k = idx & 127;
    float v = p.w[m][k * 128 + n];
    u16 hi = f2bf(v);
    p.buf[m][idx] = hi;
    p.buf[m][idx + 16384] = f2bf(v - bf2f(hi));
}

// ===========================================================================
// fused MLP: 4 row-tiles per iteration (160 MFMA per barrier-pair), A hi-only,
// W hi/lo, H hi/lo via LDS. Barrier-free A prefetch between the two barriers.
// ===========================================================================
#define HS 136
__global__ __launch_bounds__(256, 2) void fused_mlp(const u16* __restrict__ Ah,
                                                    const u16* __restrict__ W1,
                                                    const float* __restrict__ b1,
                                                    const u16* __restrict__ W2,
                                                    const float* __restrict__ b2,
                                                    float* __restrict__ Cf,
                                                    u16* __restrict__ Cb, int mode) {
    __shared__ u16 Hh[64 * HS];
    __shared__ u16 Hl[64 * HS];
    int tid = threadIdx.x;
    int lane = tid & 63, wave = tid >> 6;
    int m16 = lane & 15, quad = lane >> 4;
    int colBase = wave * 32;

    bf16x8 W1H[2][4], W1L[2][4], W2H[2][4], W2L[2][4];
#pragma unroll
    for (int nt = 0; nt < 2; ++nt) {
        int n = colBase + nt * 16 + m16;
#pragma unroll
        for (int kb = 0; kb < 4; ++kb) {
            int off = n * 128 + kb * 32 + quad * 8;
            W1H[nt][kb] = *(const bf16x8*)(W1 + off);
            W1L[nt][kb] = *(const bf16x8*)(W1 + off + 16384);
            W2H[nt][kb] = *(const bf16x8*)(W2 + off);
            W2L[nt][kb] = *(const bf16x8*)(W2 + off + 16384);
        }
    }
    float b1v[2][4], b2v[2][4];
#pragma unroll
    for (int nt = 0; nt < 2; ++nt)
#pragma unroll
        for (int rg = 0; rg < 4; ++rg) {
            int col = colBase + nt * 16 + quad * 4 + rg;
            b1v[nt][rg] = b1[col];
            b2v[nt][rg] = b2[col];
        }

    f32x4 z = {0.f, 0.f, 0.f, 0.f};
    bf16x8 aH[4][4];

    int t0 = blockIdx.x * 4;
    if (t0 < TILES) {
#pragma unroll
        for (int p = 0; p < 4; ++p) {
            const u16* ah = Ah + (size_t)((t0 + p) * 16 + m16) * 128 + quad * 8;
#pragma unroll
            for (int kb = 0; kb < 4; ++kb)
                aH[p][kb] = *(const bf16x8*)(ah + kb * 32);
        }
    }

    for (; t0 < TILES; t0 += 4 * GRID_MLP) {
        f32x4 acc[4][2];
#pragma unroll
        for (int p = 0; p < 4; ++p) { acc[p][0] = z; acc[p][1] = z; }

        // ---- pass 1: (W1H + W1L) x aH ----
#pragma unroll
        for (int kb = 0; kb < 4; ++kb) {
#pragma unroll
            for (int p = 0; p < 4; ++p) {
                acc[p][0] = MFMA(W1H[0][kb], aH[p][kb], acc[p][0]);
                acc[p][1] = MFMA(W1H[1][kb], aH[p][kb], acc[p][1]);
                acc[p][0] = MFMA(W1L[0][kb], aH[p][kb], acc[p][0]);
                acc[p][1] = MFMA(W1L[1][kb], aH[p][kb], acc[p][1]);
            }
        }

        __syncthreads();   // prev iteration's pass-2 H reads complete

        // ---- epilogue 1: bias+relu+split -> LDS ----
#pragma unroll
        for (int p = 0; p < 4; ++p) {
#pragma unroll
            for (int nt = 0; nt < 2; ++nt) {
                ushort4 hv, lv;
#pragma unroll
                for (int rg = 0; rg < 4; ++rg) {
                    float v = fmaxf(acc[p][nt][rg] + b1v[nt][rg], 0.f);
                    u16 hi = f2bf(v);
                    ((u16*)&hv)[rg] = hi;
                    ((u16*)&lv)[rg] = f2bf(v - bf2f(hi));
                }
                int off = (p * 16 + m16) * HS + colBase + nt * 16 + quad * 4;
                *(ushort4*)&Hh[off] = hv;
                *(ushort4*)&Hl[off] = lv;
            }
        }
        __syncthreads();   // H visible to all waves

        // ---- prefetch next iter's A frags into now-dead aH ----
        int nt0 = t0 + 4 * GRID_MLP;
        if (nt0 < TILES) {
#pragma unroll
            for (int p = 0; p < 4; ++p) {
                const u16* ah = Ah + (size_t)((nt0 + p) * 16 + m16) * 128 + quad * 8;
#pragma unroll
                for (int kb = 0; kb < 4; ++kb)
                    aH[p][kb] = *(const bf16x8*)(ah + kb * 32);
            }
        }

        // ---- pass 2: W2 x H (H hi/lo) ----
        f32x4 acc2[4][2];
#pragma unroll
        for (int p = 0; p < 4; ++p) { acc2[p][0] = z; acc2[p][1] = z; }
#pragma unroll
        for (int kb = 0; kb < 4; ++kb) {
#pragma unroll
            for (int p = 0; p < 4; ++p) {
                int off = (p * 16 + m16) * HS + kb * 32 + quad * 8;
                bf16x8 hH = *(const bf16x8*)(&Hh[off]);
                bf16x8 hL = *(const bf16x8*)(&Hl[off]);
                acc2[p][0] = MFMA(W2H[0][kb], hH, acc2[p][0]);
                acc2[p][1] = MFMA(W2H[1][kb], hH, acc2[p][1]);
                acc2[p][0] = MFMA(W2H[0][kb], hL, acc2[p][0]);
                acc2[p][1] = MFMA(W2H[1][kb], hL, acc2[p][1]);
                acc2[p][0] = MFMA(W2L[0][kb], hH, acc2[p][0]);
                acc2[p][1] = MFMA(W2L[1][kb], hH, acc2[p][1]);
            }
        }

        // ---- epilogue 2: bias (+relu) -> global, vectorized ----
#pragma unroll
        for (int p = 0; p < 4; ++p) {
            size_t row = (size_t)(t0 + p) * 16 + m16;
#pragma unroll
            for (int nt = 0; nt < 2; ++nt) {
                int col = colBase + nt * 16 + quad * 4;
                if (mode) {
                    ushort4 o;
#pragma unroll
                    for (int rg = 0; rg < 4; ++rg)
                        ((u16*)&o)[rg] = f2bf(fmaxf(acc2[p][nt][rg] + b2v[nt][rg], 0.f));
                    *(ushort4*)(Cb + row * 128 + col) = o;
                } else {
                    float4 o;
                    o.x = acc2[p][nt][0] + b2v[nt][0];
                    o.y = acc2[p][nt][1] + b2v[nt][1];
                    o.z = acc2[p][nt][2] + b2v[nt][2];
                    o.w = acc2[p][nt][3] + b2v[nt][3];
                    *(float4*)(Cf + row * 128 + col) = o;
                }
            }
        }
    }
}

// ===========================================================================
// pool stage 1: segment-boundary flush into sums (batch sorted)
// ===========================================================================
__global__ __launch_bounds__(256) void psum_kernel(const float* __restrict__ h,
                                                   const int* __restrict__ batch,
                                                   float* __restrict__ sums) {
    __shared__ int sBatch[128];
    int blk = blockIdx.x, t = threadIdx.x;
    int n0 = blk * 128;
    int nEnd = min(n0 + 128, N_NODES);
    if (t < 128 && n0 + t < N_NODES) sBatch[t] = batch[n0 + t];
    __syncthreads();

    int j = t & 127;
    int half = t >> 7;
    int s = n0 + half * 64;
    int e = min(s + 64, nEnd);

    float acc = 0.f;
    int cur = -1;
    for (int n = s; n < e; ++n) {
        int g = sBatch[n - n0];
        if (g != cur) {
            if (cur >= 0) atomicAdd(&sums[cur * 128 + j], acc);
            cur = g;
            acc = 0.f;
        }
        acc += h[(size_t)n * 128 + j];
    }
    if (cur >= 0) atomicAdd(&sums[cur * 128 + j], acc);
}

// pool stage 2: counts by binary search, divide.
__global__ __launch_bounds__(128) void pdiv_kernel(const float* __restrict__ sums,
                                                   const int* __restrict__ batch,
                                                   float* __restrict__ out) {
    __shared__ int sB[2];
    int g = blockIdx.x;
    if (threadIdx.x < 2) {
        int target = g + threadIdx.x;
        int lo = 0, hi = N_NODES;
        while (lo < hi) {
            int m = (lo + hi) >> 1;
            if (batch[m] < target) lo = m + 1; else hi = m;
        }
        sB[threadIdx.x] = lo;
    }
    __syncthreads();
    float cnt = (float)(sB[1] - sB[0]);
    out[g * 128 + threadIdx.x] = sums[g * 128 + threadIdx.x] / fmaxf(cnt, 1.f);
}

// ===========================================================================
extern "C" void kernel_launch(void* const* d_in, const int* in_sizes, int n_in,
                              void* d_out, int out_size, void* d_ws, size_t ws_size,
                              hipStream_t stream) {
    const float* x     = (const float*)d_in[0];
    const int*   ei    = (const int*)d_in[1];
    const int*   batch = (const int*)d_in[2];
    const int*   eSrc  = ei;
    const int*   eDst  = ei + N_EDGES;

    const float* W1[3] = {(const float*)d_in[3], (const float*)d_in[7],  (const float*)d_in[11]};
    const float* b1[3] = {(const float*)d_in[4], (const float*)d_in[8],  (const float*)d_in[12]};
    const float* W2[3] = {(const float*)d_in[5], (const float*)d_in[9],  (const float*)d_in[13]};
    const float* b2[3] = {(const float*)d_in[6], (const float*)d_in[10], (const float*)d_in[14]};

    // workspace layout
    float* P2 = (float*)d_ws;                          // [N_PAD,128] fp32 (layer-2 out)
    u16*   hb = (u16*)(P2 + (size_t)N_PAD * DIM);      // bf16 hi plane
    u16*   Ah = hb + (size_t)N_PAD * DIM;              // agg hi plane
    u16*   Wb = Ah + (size_t)N_PAD * DIM;              // 6 x 32768 u16
    int*   row_ptr = (int*)(Wb + 6 * 32768);           // N_NODES + 8
    u32*   cursorB = (u32*)(row_ptr + N_NODES + 8);    // 128
    int*   csr     = (int*)(cursorB + 128);            // N_EDGES
    float* sums    = (float*)(csr + N_EDGES);          // [128,128]
    u32*   pairs   = (u32*)P2;                         // aliases P2 (disjoint lifetime)

    // ---- CSR build ----
    hipMemsetAsync(cursorB, 0, 128 * sizeof(u32), stream);
    bucket1_kernel<<<B1_GRID, 256, 0, stream>>>(eSrc, eDst, cursorB, pairs);
    bucket2_kernel<<<NBKT, 1024, 0, stream>>>(cursorB, pairs, row_ptr, csr);

    // ---- x -> bf16 plane, W prep, zero pool sums ----
    xprep_kernel<<<(N_NODES * 32 + 255) / 256, 256, 0, stream>>>(x, hb);
    WPrepArgs wp;
    for (int l = 0; l < 3; ++l) {
        wp.w[2 * l]       = W1[l];
        wp.w[2 * l + 1]   = W2[l];
        wp.buf[2 * l]     = Wb + (size_t)(2 * l) * 32768;
        wp.buf[2 * l + 1] = Wb + (size_t)(2 * l + 1) * 32768;
    }
    wprep_kernel<<<dim3(64, 6), 256, 0, stream>>>(wp);
    hipMemsetAsync(sums, 0, N_GRAPHS * DIM * sizeof(float), stream);

    const int aggGrid = (N_NODES * 32 + 255) / 256;

    for (int l = 0; l < 3; ++l) {
        agg_kernel<<<aggGrid, 256, 0, stream>>>(hb, row_ptr, csr, Ah);
        fused_mlp<<<GRID_MLP, 256, 0, stream>>>(Ah,
                                                Wb + (size_t)(2 * l) * 32768, b1[l],
                                                Wb + (size_t)(2 * l + 1) * 32768, b2[l],
                                                P2, hb, (l < 2) ? 1 : 0);
    }
    psum_kernel<<<POOL_BLKS, 256, 0, stream>>>(P2, batch, sums);
    pdiv_kernel<<<N_GRAPHS, 128, 0, stream>>>(sums, batch, (float*)d_out);
}